// Round 14
// baseline (1078.706 us; speedup 1.0000x reference)
//
#include <hip/hip_runtime.h>
#include <hip/hip_bf16.h>
#include <stdint.h>

#define N_NODES 50000
#define N_EDGES 800000
#define HID 128
#define NODE_IN 16
#define NODE_OUT 3
#define NODE_TILES 782     // ceil(50000 / 64)
#define SCAN_BLOCKS 196    // ceil(50000 / 256)
#define EPG 32             // edges per 16-thread group
#define NGROUPS (N_EDGES / EPG)   // 25000

typedef __attribute__((ext_vector_type(8))) short short8;
typedef __attribute__((ext_vector_type(4))) float f32x4;

__device__ __forceinline__ unsigned short f2bf(float f) {
    union { float f; unsigned int u; } v; v.f = f;
    unsigned int u = v.u;
    u += 0x7fff + ((u >> 16) & 1);   // round-to-nearest-even
    return (unsigned short)(u >> 16);
}
__device__ __forceinline__ float bf2f(unsigned short s) {
    union { unsigned int u; float f; } v; v.u = ((unsigned int)s) << 16;
    return v.f;
}
__device__ __forceinline__ float bfu_lo(unsigned int u) {
    union { unsigned int u; float f; } v; v.u = u << 16; return v.f;
}
__device__ __forceinline__ float bfu_hi(unsigned int u) {
    union { unsigned int u; float f; } v; v.u = u & 0xffff0000u; return v.f;
}

// ---------------- K1: degree histogram (+ per-edge rank) + M-fold ----------------
__global__ void k1_hist_mfold(const int* __restrict__ colp, int* __restrict__ cnt,
                              int* __restrict__ rank,
                              const float* __restrict__ edge_w2, const float* __restrict__ node_w1,
                              const float* __restrict__ edge_b2,
                              float* __restrict__ Mtmp, float* __restrict__ Vtmp) {
    for (int e = blockIdx.x * 256 + threadIdx.x; e < N_EDGES; e += gridDim.x * 256)
        rank[e] = atomicAdd(&cnt[colp[e]], 1);   // old value = within-dest rank
    for (int d = blockIdx.x * 256 + threadIdx.x; d < 3 * 16384; d += gridDim.x * 256) {
        int L = d / 16384, rem = d & 16383;
        int k = rem >> 7, n = rem & 127;
        const float* w2  = edge_w2 + (size_t)L * 16384;
        const float* w1b = node_w1 + (size_t)L * 32768 + 16384;   // bottom-half rows
        float acc = 0.f;
        #pragma unroll 4
        for (int j = 0; j < 128; j++) acc += w2[k * 128 + j] * w1b[j * 128 + n];
        Mtmp[d] = acc;
        if (k == 0) {
            const float* b2 = edge_b2 + (size_t)L * 128;
            float vv = 0.f;
            #pragma unroll 4
            for (int j = 0; j < 128; j++) vv += b2[j] * w1b[j * 128 + n];
            Vtmp[L * 128 + n] = vv;
        }
    }
}

// ---------------- K2a: parallel scan1 (blocks < SCAN_BLOCKS) + weight swizzles ----------------
// swz per-layer layout: +0 edge w1cat (32768), [32768..49152) unused,
//                       +49152 node w1-modified [W1top; M] (32768), +81920 node w2 (16384)
__global__ __launch_bounds__(256) void k2a_scan1_swizzle(
    const int* __restrict__ cnt, int* __restrict__ ex, int* __restrict__ bsums,
    const float* __restrict__ edge_w1, const float* __restrict__ node_w1,
    const float* __restrict__ node_w2, const float* __restrict__ Mtmp,
    unsigned short* __restrict__ swz) {
    __shared__ int s[256];
    int b = blockIdx.x, t = threadIdx.x;
    if (b < SCAN_BLOCKS) {
        int i = b * 256 + t;
        int v = (i < N_NODES) ? cnt[i] : 0;
        s[t] = v;
        __syncthreads();
        for (int off = 1; off < 256; off <<= 1) {
            int u = (t >= off) ? s[t - off] : 0;
            __syncthreads();
            s[t] += u;
            __syncthreads();
        }
        if (i < N_NODES) ex[i] = s[t] - v;
        if (t == 255) bsums[b] = s[255];
    } else {
        for (int d = (b - SCAN_BLOCKS) * 256 + t; d < 3 * 98304;
             d += (gridDim.x - SCAN_BLOCKS) * 256) {
            int L = d / 98304;
            int rem = d - L * 98304;
            unsigned short* base = swz + L * 98304;
            if (rem < 32768) {
                // edge w1 combined [128 x 256] B-frags (16 n-tiles)
                const float* w1 = edge_w1 + (size_t)L * 32768;
                int j = rem & 7, ll = (rem >> 3) & 63, tt = rem >> 9;
                int nt = tt & 15, kt = tt >> 4;
                int k = kt * 32 + ((ll >> 4) << 3) + j;
                int cc = nt * 16 + (ll & 15);
                float v = (cc < 128) ? w1[k * 128 + cc] : w1[(128 + k) * 128 + (cc - 128)];
                base[rem] = f2bf(v);
            } else if (rem < 49152) {
                // unused slot (edge w2 folded into node w1 via M)
            } else if (rem < 81920) {
                int d2 = rem - 49152;
                int j = d2 & 7, ll = (d2 >> 3) & 63, tt = d2 >> 9;
                int nt = tt & 7, kt = tt >> 3;
                int k = kt * 32 + ((ll >> 4) << 3) + j, n = (nt << 4) + (ll & 15);
                float v = (k < 128) ? node_w1[(size_t)L * 32768 + k * 128 + n]
                                    : Mtmp[(size_t)L * 16384 + (k - 128) * 128 + n];
                base[rem] = f2bf(v);
            } else {
                int d2 = rem - 81920;
                const float* src = node_w2 + (size_t)L * 16384;
                int j = d2 & 7, ll = (d2 >> 3) & 63, tt = d2 >> 9;
                int nt = tt & 7, kt = tt >> 3;
                int k = kt * 32 + ((ll >> 4) << 3) + j, n = (nt << 4) + (ll & 15);
                base[rem] = f2bf(src[k * 128 + n]);
            }
        }
    }
}

// ---------------- K2b: scan of the 196 block sums (single block) ----------------
__global__ void k2b_scan2(int* bsums) {
    __shared__ int s[256];
    int t = threadIdx.x;
    int v = (t < SCAN_BLOCKS) ? bsums[t] : 0;
    s[t] = v;
    __syncthreads();
    for (int off = 1; off < 256; off <<= 1) {
        int u = (t >= off) ? s[t - off] : 0;
        __syncthreads();
        s[t] += u;
        __syncthreads();
    }
    if (t < SCAN_BLOCKS) bsums[t] = s[t] - v;
}

// ---------------- K3a: atomic-free scatter, packed 8B writes ----------------
__global__ void k3a_scatter(const int* __restrict__ rowp, const int* __restrict__ colp,
                            const int* __restrict__ ex, const int* __restrict__ bsums,
                            const int* __restrict__ rank, int2* __restrict__ rc_sorted) {
    int e = blockIdx.x * 256 + threadIdx.x;
    if (e >= N_EDGES) return;
    int c = colp[e];
    int pos = ex[c] + bsums[c >> 8] + rank[e];
    rc_sorted[pos] = make_int2(rowp[e], c);
}

// ---------------- K3b: encoder + S/D layer 0 ----------------
__global__ __launch_bounds__(256, 4) void k3b_encoder_sd(
    const float* __restrict__ x, const float* __restrict__ enc_w, const float* __restrict__ enc_b,
    const unsigned short* __restrict__ w1c, unsigned short* __restrict__ h,
    unsigned short* __restrict__ S, unsigned short* __restrict__ D)
{
    __shared__ float wts[NODE_IN * HID];
    __shared__ float bts[HID];
    __shared__ float xs[64][NODE_IN];
    __shared__ unsigned short hs[64][136];
    int t = threadIdx.x, wave = t >> 6, l = t & 63, q = l >> 4, l16 = l & 15;
    int n0 = blockIdx.x * 64;
    int nt0s = wave * 4;

    for (int i = t; i < NODE_IN * HID; i += 256) wts[i] = enc_w[i];
    if (t < HID) bts[t] = enc_b[t];
    for (int i = t; i < 64 * NODE_IN; i += 256) {
        int nl = i >> 4, ii = i & 15;
        int n = n0 + nl;
        xs[nl][ii] = (n < N_NODES) ? x[n * NODE_IN + ii] : 0.f;
    }
    short8 wr[4][4];
    #pragma unroll
    for (int kt = 0; kt < 4; kt++)
        #pragma unroll
        for (int i = 0; i < 4; i++)
            wr[kt][i] = *(const short8*)(w1c + ((kt * 16 + nt0s + i) * 64 + l) * 8);
    __syncthreads();

    for (int o = t; o < 64 * HID; o += 256) {
        int nl = o >> 7, cc = o & 127;
        float acc = bts[cc];
        #pragma unroll
        for (int i = 0; i < NODE_IN; i++) acc += xs[nl][i] * wts[i * HID + cc];
        unsigned short hb = f2bf(acc);
        hs[nl][cc] = hb;
        int n = n0 + nl;
        if (n < N_NODES) h[n * HID + cc] = hb;
    }
    __syncthreads();

    f32x4 acc[4][4];
    #pragma unroll
    for (int g = 0; g < 4; g++)
        #pragma unroll
        for (int i = 0; i < 4; i++) acc[g][i] = (f32x4){0.f, 0.f, 0.f, 0.f};
    #pragma unroll
    for (int kt = 0; kt < 4; kt++) {
        #pragma unroll
        for (int g = 0; g < 4; g++) {
            short8 a = *(const short8*)&hs[g * 16 + l16][kt * 32 + q * 8];
            #pragma unroll
            for (int i = 0; i < 4; i++)
                acc[g][i] = __builtin_amdgcn_mfma_f32_16x16x32_bf16(a, wr[kt][i], acc[g][i], 0, 0, 0);
        }
    }
    #pragma unroll
    for (int i = 0; i < 4; i++) {
        int cc = (nt0s + i) * 16 + l16;
        #pragma unroll
        for (int g = 0; g < 4; g++)
            #pragma unroll
            for (int r = 0; r < 4; r++) {
                int n = n0 + g * 16 + q * 4 + r;
                if (n < N_NODES) {
                    unsigned short v = f2bf(acc[g][i][r]);
                    if (cc < 128) S[n * HID + cc] = v;
                    else          D[n * HID + (cc - 128)] = v;
                }
            }
    }
}

// ---------------- edge: barrier-free streaming gather + register segreduce ----------------
// 16-thread group owns EPG contiguous dest-sorted edges; fp32 accumulator + current
// D-row chunk (+b1) live in registers; S gathers staged 8 deep; flush on dest change.
__global__ __launch_bounds__(256) void edge_kernel(
    const unsigned short* __restrict__ S, const unsigned short* __restrict__ D,
    const int2* __restrict__ rc_sorted,
    const float* __restrict__ b1, float* __restrict__ aggH)
{
    int t = threadIdx.x;
    int ch = t & 15;
    int gid = (blockIdx.x * 256 + t) >> 4;
    if (gid >= NGROUPS) return;
    int e0 = gid * EPG;

    float b1v[8];
    #pragma unroll
    for (int j = 0; j < 8; j++) b1v[j] = b1[ch * 8 + j];

    float acc[8];
    #pragma unroll
    for (int j = 0; j < 8; j++) acc[j] = 0.f;

    int cur = rc_sorted[e0].y;
    float dreg[8];
    {
        short8 dv = *(const short8*)(D + (size_t)cur * HID + ch * 8);
        #pragma unroll
        for (int p = 0; p < 4; p++) {
            unsigned int ud = ((const unsigned int*)&dv)[p];
            dreg[p * 2]     = bfu_lo(ud) + b1v[p * 2];
            dreg[p * 2 + 1] = bfu_hi(ud) + b1v[p * 2 + 1];
        }
    }

    #pragma unroll
    for (int base = 0; base < EPG; base += 8) {
        // stage 8 edges: indices then S-chunks (8 independent loads in flight)
        int2 rcb[8];
        #pragma unroll
        for (int i = 0; i < 8; i++) rcb[i] = rc_sorted[e0 + base + i];
        short8 sv[8];
        #pragma unroll
        for (int i = 0; i < 8; i++)
            sv[i] = *(const short8*)(S + (size_t)rcb[i].x * HID + ch * 8);

        #pragma unroll
        for (int i = 0; i < 8; i++) {
            int c = rcb[i].y;
            if (c != cur) {   // group-uniform branch
                #pragma unroll
                for (int j = 0; j < 8; j++)
                    unsafeAtomicAdd(&aggH[(size_t)cur * HID + ch * 8 + j], acc[j]);
                #pragma unroll
                for (int j = 0; j < 8; j++) acc[j] = 0.f;
                short8 dv = *(const short8*)(D + (size_t)c * HID + ch * 8);
                #pragma unroll
                for (int p = 0; p < 4; p++) {
                    unsigned int ud = ((const unsigned int*)&dv)[p];
                    dreg[p * 2]     = bfu_lo(ud) + b1v[p * 2];
                    dreg[p * 2 + 1] = bfu_hi(ud) + b1v[p * 2 + 1];
                }
                cur = c;
            }
            #pragma unroll
            for (int p = 0; p < 4; p++) {
                unsigned int us = ((const unsigned int*)&sv[i])[p];
                float v0 = bfu_lo(us) + dreg[p * 2];
                float v1 = bfu_hi(us) + dreg[p * 2 + 1];
                acc[p * 2]     += v0 > 0.f ? v0 : 0.f;
                acc[p * 2 + 1] += v1 > 0.f ? v1 : 0.f;
            }
        }
    }
    #pragma unroll
    for (int j = 0; j < 8; j++)
        unsafeAtomicAdd(&aggH[(size_t)cur * HID + ch * 8 + j], acc[j]);
}

// ---------------- node MLP (folded GEMM1) + residual + (next S/D | decoder) ----------------
template<int LAST>
__global__ __launch_bounds__(256, 4) void node_kernel(
    unsigned short* __restrict__ h, float* __restrict__ aggH, const int* __restrict__ cnt,
    const unsigned short* __restrict__ w1m_s, const float* __restrict__ b1,
    const float* __restrict__ vfold,
    const unsigned short* __restrict__ w2s, const float* __restrict__ b2,
    const unsigned short* __restrict__ w1c_next,
    unsigned short* __restrict__ S, unsigned short* __restrict__ D,
    const float* __restrict__ dec_w, const float* __restrict__ dec_b, float* __restrict__ out)
{
    __shared__ unsigned short in_h[64][136];   // old h -> new h after residual
    __shared__ unsigned short in_a[64][136];   // bf16(aggH); reused as hid after GEMM1
    __shared__ int cnt_s[64];
    __shared__ float dw[HID * NODE_OUT];
    __shared__ float db[NODE_OUT];
    int t = threadIdx.x, wave = t >> 6, l = t & 63, q = l >> 4, l16 = l & 15;
    int nt0 = wave * 2, nt0s = wave * 4;
    int n0 = blockIdx.x * 64;

    if (LAST) {
        for (int i = t; i < HID * NODE_OUT; i += 256) dw[i] = dec_w[i];
        if (t < NODE_OUT) db[t] = dec_b[t];
    }

    // stage: h -> in_h, bf16(aggH) -> in_a (re-zero aggH for next layer), cnt
    #pragma unroll
    for (int it = 0; it < 8; it++) {
        int g = it * 256 + t;
        int nl = g >> 5, sub = g & 31, half = sub >> 4, li = sub & 15;
        int n = n0 + nl;
        short8 v = (short8){0, 0, 0, 0, 0, 0, 0, 0};
        if (n < N_NODES) {
            if (half == 0) {
                v = *(const short8*)(h + n * HID + li * 8);
            } else {
                float* ap = aggH + n * HID + li * 8;
                f32x4 a0 = *(f32x4*)ap, a1 = *(f32x4*)(ap + 4);
                #pragma unroll
                for (int j = 0; j < 4; j++) {
                    ((unsigned short*)&v)[j]     = f2bf(a0[j]);
                    ((unsigned short*)&v)[4 + j] = f2bf(a1[j]);
                }
                if (!LAST) {
                    *(f32x4*)ap       = (f32x4){0.f, 0.f, 0.f, 0.f};
                    *(f32x4*)(ap + 4) = (f32x4){0.f, 0.f, 0.f, 0.f};
                }
            }
        }
        if (half == 0) *(short8*)&in_h[nl][li * 8] = v;
        else           *(short8*)&in_a[nl][li * 8] = v;
    }
    if (t < 64) cnt_s[t] = (n0 + t < N_NODES) ? cnt[n0 + t] : 0;
    __syncthreads();

    float b1r0 = b1[nt0 * 16 + l16], b1r1 = b1[(nt0 + 1) * 16 + l16];
    float vr0 = vfold[nt0 * 16 + l16], vr1 = vfold[(nt0 + 1) * 16 + l16];
    float b2r0 = b2[nt0 * 16 + l16], b2r1 = b2[(nt0 + 1) * 16 + l16];

    // GEMM1 (K=256, B = [W1top; M] folded): h@W1top + aggH@M
    f32x4 acc[4][2];
    #pragma unroll
    for (int g = 0; g < 4; g++)
        #pragma unroll
        for (int j = 0; j < 2; j++) acc[g][j] = (f32x4){0.f, 0.f, 0.f, 0.f};
    #pragma unroll
    for (int kt = 0; kt < 8; kt++) {
        short8 b0 = *(const short8*)(w1m_s + ((kt * 8 + nt0)     * 64 + l) * 8);
        short8 b1v = *(const short8*)(w1m_s + ((kt * 8 + nt0 + 1) * 64 + l) * 8);
        #pragma unroll
        for (int g = 0; g < 4; g++) {
            short8 a = (kt < 4) ? *(const short8*)&in_h[g * 16 + l16][kt * 32 + q * 8]
                                : *(const short8*)&in_a[g * 16 + l16][(kt - 4) * 32 + q * 8];
            acc[g][0] = __builtin_amdgcn_mfma_f32_16x16x32_bf16(a, b0, acc[g][0], 0, 0, 0);
            acc[g][1] = __builtin_amdgcn_mfma_f32_16x16x32_bf16(a, b1v, acc[g][1], 0, 0, 0);
        }
    }
    __syncthreads();   // all in_a reads complete before hid overwrite

    // epilogue: + b1 + deg*v -> relu -> hid (aliases in_a)
    #pragma unroll
    for (int j = 0; j < 2; j++) {
        float bv = j ? b1r1 : b1r0;
        float vv = j ? vr1 : vr0;
        #pragma unroll
        for (int g = 0; g < 4; g++)
            #pragma unroll
            for (int r = 0; r < 4; r++) {
                int m2 = g * 16 + q * 4 + r;
                float v = acc[g][j][r] + bv + (float)cnt_s[m2] * vv;
                v = v > 0.f ? v : 0.f;
                in_a[m2][(nt0 + j) * 16 + l16] = f2bf(v);
            }
    }
    __syncthreads();

    // GEMM2n (K=128) -> residual -> h + in_h
    f32x4 acc2[4][2];
    #pragma unroll
    for (int g = 0; g < 4; g++)
        #pragma unroll
        for (int j = 0; j < 2; j++) acc2[g][j] = (f32x4){0.f, 0.f, 0.f, 0.f};
    #pragma unroll
    for (int kt = 0; kt < 4; kt++) {
        short8 b0 = *(const short8*)(w2s + ((kt * 8 + nt0)     * 64 + l) * 8);
        short8 b1v = *(const short8*)(w2s + ((kt * 8 + nt0 + 1) * 64 + l) * 8);
        #pragma unroll
        for (int g = 0; g < 4; g++) {
            short8 a = *(const short8*)&in_a[g * 16 + l16][kt * 32 + q * 8];
            acc2[g][0] = __builtin_amdgcn_mfma_f32_16x16x32_bf16(a, b0, acc2[g][0], 0, 0, 0);
            acc2[g][1] = __builtin_amdgcn_mfma_f32_16x16x32_bf16(a, b1v, acc2[g][1], 0, 0, 0);
        }
    }
    #pragma unroll
    for (int j = 0; j < 2; j++) {
        float bv = j ? b2r1 : b2r0;
        #pragma unroll
        for (int g = 0; g < 4; g++)
            #pragma unroll
            for (int r = 0; r < 4; r++) {
                float v = acc2[g][j][r] + bv;
                int m2 = g * 16 + q * 4 + r;
                int n = n0 + m2;
                if (n < N_NODES) {
                    int c = (nt0 + j) * 16 + l16;
                    unsigned short nh = f2bf(bf2f(in_h[m2][c]) + v);   // residual (same-thread cell)
                    if (!LAST) h[n * HID + c] = nh;
                    in_h[m2][c] = nh;
                }
            }
    }
    __syncthreads();

    if (!LAST) {
        // next-layer S/D from new h (in_h), in 2 register-light passes
        #pragma unroll
        for (int p = 0; p < 2; p++) {
            short8 wr[4][2];
            #pragma unroll
            for (int kt = 0; kt < 4; kt++) {
                wr[kt][0] = *(const short8*)(w1c_next + ((kt * 16 + nt0s + p * 2)     * 64 + l) * 8);
                wr[kt][1] = *(const short8*)(w1c_next + ((kt * 16 + nt0s + p * 2 + 1) * 64 + l) * 8);
            }
            f32x4 accs[4][2];
            #pragma unroll
            for (int g = 0; g < 4; g++)
                #pragma unroll
                for (int i = 0; i < 2; i++) accs[g][i] = (f32x4){0.f, 0.f, 0.f, 0.f};
            #pragma unroll
            for (int kt = 0; kt < 4; kt++) {
                #pragma unroll
                for (int g = 0; g < 4; g++) {
                    short8 a = *(const short8*)&in_h[g * 16 + l16][kt * 32 + q * 8];
                    accs[g][0] = __builtin_amdgcn_mfma_f32_16x16x32_bf16(a, wr[kt][0], accs[g][0], 0, 0, 0);
                    accs[g][1] = __builtin_amdgcn_mfma_f32_16x16x32_bf16(a, wr[kt][1], accs[g][1], 0, 0, 0);
                }
            }
            #pragma unroll
            for (int i = 0; i < 2; i++) {
                int c = (nt0s + p * 2 + i) * 16 + l16;
                #pragma unroll
                for (int g = 0; g < 4; g++)
                    #pragma unroll
                    for (int r = 0; r < 4; r++) {
                        int n = n0 + g * 16 + q * 4 + r;
                        if (n < N_NODES) {
                            unsigned short v = f2bf(accs[g][i][r]);
                            if (c < 128) S[n * HID + c] = v;
                            else         D[n * HID + (c - 128)] = v;
                        }
                    }
            }
        }
    } else {
        // decoder: out = new_h @ dec_w + dec_b
        if (t < 64 * NODE_OUT) {
            int nl = t / 3, o = t - 3 * nl;
            int n = n0 + nl;
            if (n < N_NODES) {
                float a = db[o];
                #pragma unroll 4
                for (int k = 0; k < HID; k++) a += bf2f(in_h[nl][k]) * dw[k * 3 + o];
                out[n * 3 + o] = a;
            }
        }
    }
}

extern "C" void kernel_launch(void* const* d_in, const int* in_sizes, int n_in,
                              void* d_out, int out_size, void* d_ws, size_t ws_size,
                              hipStream_t stream) {
    const float* x       = (const float*)d_in[0];
    const int*   ei      = (const int*)d_in[1];
    const float* enc_w   = (const float*)d_in[2];
    const float* enc_b   = (const float*)d_in[3];
    const float* dec_w   = (const float*)d_in[4];
    const float* dec_b   = (const float*)d_in[5];
    const float* edge_w1 = (const float*)d_in[6];
    const float* edge_b1 = (const float*)d_in[7];
    const float* edge_w2 = (const float*)d_in[8];
    const float* edge_b2 = (const float*)d_in[9];
    const float* node_w1 = (const float*)d_in[10];
    const float* node_b1 = (const float*)d_in[11];
    const float* node_w2 = (const float*)d_in[12];
    const float* node_b2 = (const float*)d_in[13];

    char* ws = (char*)d_ws;
    unsigned short* h    = (unsigned short*)ws;                    // 12.8 MB
    float*          aggH = (float*)(ws + 12800000);                // 25.6 MB
    unsigned short* swz  = (unsigned short*)(ws + 38400000);       // 589,824 B
    int* cnt             = (int*)(ws + 38989824);                  // 200,000 B (degrees)
    int* ex              = (int*)(ws + 39189824);                  // 200,000 B
    int* bsums           = (int*)(ws + 39389824);                  // 1,024 B
    int2* rc_sorted      = (int2*)(ws + 39390848);                 // 6.4 MB
    unsigned short* Sbuf = (unsigned short*)(ws + 45790848);       // 12.8 MB
    unsigned short* Dbuf = (unsigned short*)(ws + 58590848);       // 12.8 MB
    float* Mtmp          = (float*)(ws + 71390848);                // 196,608 B
    float* Vtmp          = (float*)(ws + 71587456);                // 1,536 B -> end 71,588,992
    // rank overlays the Dbuf region: written in k1, consumed in k3a,
    // before Dbuf's first write in k3b. No extra workspace.
    int* rank            = (int*)(ws + 58590848);                  // 3.2 MB (aliases Dbuf)

    const int* rowp = ei;            // edge_index[0] = source
    const int* colp = ei + N_EDGES;  // edge_index[1] = destination

    hipMemsetAsync(cnt, 0, (size_t)N_NODES * 4, stream);
    hipMemsetAsync(aggH, 0, (size_t)N_NODES * HID * 4, stream);    // layer-0 aggH zero

    k1_hist_mfold<<<1024, 256, 0, stream>>>(colp, cnt, rank, edge_w2, node_w1, edge_b2,
                                            Mtmp, Vtmp);
    k2a_scan1_swizzle<<<SCAN_BLOCKS + 288, 256, 0, stream>>>(cnt, ex, bsums, edge_w1,
                                                             node_w1, node_w2, Mtmp, swz);
    k2b_scan2<<<1, 256, 0, stream>>>(bsums);
    k3a_scatter<<<3125, 256, 0, stream>>>(rowp, colp, ex, bsums, rank, rc_sorted);
    k3b_encoder_sd<<<NODE_TILES, 256, 0, stream>>>(x, enc_w, enc_b, swz /*L0 w1cat*/, h,
                                                   Sbuf, Dbuf);

    const int edge_blocks = (NGROUPS * 16 + 255) / 256;   // 1563
    for (int L = 0; L < 3; L++) {
        unsigned short* base = swz + (size_t)L * 98304;
        unsigned short* next = swz + (size_t)(L + 1) * 98304;   // w1cat of next layer
        edge_kernel<<<edge_blocks, 256, 0, stream>>>(Sbuf, Dbuf, rc_sorted,
                                                     edge_b1 + (size_t)L * HID, aggH);
        if (L < 2) {
            node_kernel<0><<<NODE_TILES, 256, 0, stream>>>(
                h, aggH, cnt,
                base + 49152, node_b1 + (size_t)L * HID, Vtmp + (size_t)L * HID,
                base + 81920, node_b2 + (size_t)L * HID,
                next, Sbuf, Dbuf, dec_w, dec_b, (float*)d_out);
        } else {
            node_kernel<1><<<NODE_TILES, 256, 0, stream>>>(
                h, aggH, cnt,
                base + 49152, node_b1 + (size_t)L * HID, Vtmp + (size_t)L * HID,
                base + 81920, node_b2 + (size_t)L * HID,
                base /*unused*/, Sbuf, Dbuf, dec_w, dec_b, (float*)d_out);
        }
    }
}

// Round 15
// 439.755 us; speedup vs baseline: 2.4530x; 2.4530x over previous
//
#include <hip/hip_runtime.h>
#include <hip/hip_bf16.h>
#include <stdint.h>

#define N_NODES 50000
#define N_EDGES 800000
#define HID 128
#define NODE_IN 16
#define NODE_OUT 3
#define EDGE_TILES 12500   // 800000 / 64
#define NODE_TILES 782     // ceil(50000 / 64)
#define SCAN_BLOCKS 196    // ceil(50000 / 256)

typedef __attribute__((ext_vector_type(8))) short short8;
typedef __attribute__((ext_vector_type(4))) float f32x4;

__device__ __forceinline__ unsigned short f2bf(float f) {
    union { float f; unsigned int u; } v; v.f = f;
    unsigned int u = v.u;
    u += 0x7fff + ((u >> 16) & 1);   // round-to-nearest-even
    return (unsigned short)(u >> 16);
}
__device__ __forceinline__ float bf2f(unsigned short s) {
    union { unsigned int u; float f; } v; v.u = ((unsigned int)s) << 16;
    return v.f;
}
__device__ __forceinline__ float bfu_lo(unsigned int u) {
    union { unsigned int u; float f; } v; v.u = u << 16; return v.f;
}
__device__ __forceinline__ float bfu_hi(unsigned int u) {
    union { unsigned int u; float f; } v; v.u = u & 0xffff0000u; return v.f;
}

// ---------------- K1: degree histogram (+ per-edge rank) + M-fold ----------------
__global__ void k1_hist_mfold(const int* __restrict__ colp, int* __restrict__ cnt,
                              int* __restrict__ rank,
                              const float* __restrict__ edge_w2, const float* __restrict__ node_w1,
                              const float* __restrict__ edge_b2,
                              float* __restrict__ Mtmp, float* __restrict__ Vtmp) {
    for (int e = blockIdx.x * 256 + threadIdx.x; e < N_EDGES; e += gridDim.x * 256)
        rank[e] = atomicAdd(&cnt[colp[e]], 1);   // old value = within-dest rank
    for (int d = blockIdx.x * 256 + threadIdx.x; d < 3 * 16384; d += gridDim.x * 256) {
        int L = d / 16384, rem = d & 16383;
        int k = rem >> 7, n = rem & 127;
        const float* w2  = edge_w2 + (size_t)L * 16384;
        const float* w1b = node_w1 + (size_t)L * 32768 + 16384;   // bottom-half rows
        float acc = 0.f;
        #pragma unroll 4
        for (int j = 0; j < 128; j++) acc += w2[k * 128 + j] * w1b[j * 128 + n];
        Mtmp[d] = acc;
        if (k == 0) {
            const float* b2 = edge_b2 + (size_t)L * 128;
            float vv = 0.f;
            #pragma unroll 4
            for (int j = 0; j < 128; j++) vv += b2[j] * w1b[j * 128 + n];
            Vtmp[L * 128 + n] = vv;
        }
    }
}

// ---------------- K2a: parallel scan1 (blocks < SCAN_BLOCKS) + weight swizzles ----------------
// swz per-layer layout: +0 edge w1cat (32768), [32768..49152) unused,
//                       +49152 node w1-modified [W1top; M] (32768), +81920 node w2 (16384)
__global__ __launch_bounds__(256) void k2a_scan1_swizzle(
    const int* __restrict__ cnt, int* __restrict__ ex, int* __restrict__ bsums,
    const float* __restrict__ edge_w1, const float* __restrict__ node_w1,
    const float* __restrict__ node_w2, const float* __restrict__ Mtmp,
    unsigned short* __restrict__ swz) {
    __shared__ int s[256];
    int b = blockIdx.x, t = threadIdx.x;
    if (b < SCAN_BLOCKS) {
        int i = b * 256 + t;
        int v = (i < N_NODES) ? cnt[i] : 0;
        s[t] = v;
        __syncthreads();
        for (int off = 1; off < 256; off <<= 1) {
            int u = (t >= off) ? s[t - off] : 0;
            __syncthreads();
            s[t] += u;
            __syncthreads();
        }
        if (i < N_NODES) ex[i] = s[t] - v;
        if (t == 255) bsums[b] = s[255];
    } else {
        for (int d = (b - SCAN_BLOCKS) * 256 + t; d < 3 * 98304;
             d += (gridDim.x - SCAN_BLOCKS) * 256) {
            int L = d / 98304;
            int rem = d - L * 98304;
            unsigned short* base = swz + L * 98304;
            if (rem < 32768) {
                // edge w1 combined [128 x 256] B-frags (16 n-tiles)
                const float* w1 = edge_w1 + (size_t)L * 32768;
                int j = rem & 7, ll = (rem >> 3) & 63, tt = rem >> 9;
                int nt = tt & 15, kt = tt >> 4;
                int k = kt * 32 + ((ll >> 4) << 3) + j;
                int cc = nt * 16 + (ll & 15);
                float v = (cc < 128) ? w1[k * 128 + cc] : w1[(128 + k) * 128 + (cc - 128)];
                base[rem] = f2bf(v);
            } else if (rem < 49152) {
                // unused slot (edge w2 folded into node w1 via M)
            } else if (rem < 81920) {
                int d2 = rem - 49152;
                int j = d2 & 7, ll = (d2 >> 3) & 63, tt = d2 >> 9;
                int nt = tt & 7, kt = tt >> 3;
                int k = kt * 32 + ((ll >> 4) << 3) + j, n = (nt << 4) + (ll & 15);
                float v = (k < 128) ? node_w1[(size_t)L * 32768 + k * 128 + n]
                                    : Mtmp[(size_t)L * 16384 + (k - 128) * 128 + n];
                base[rem] = f2bf(v);
            } else {
                int d2 = rem - 81920;
                const float* src = node_w2 + (size_t)L * 16384;
                int j = d2 & 7, ll = (d2 >> 3) & 63, tt = d2 >> 9;
                int nt = tt & 7, kt = tt >> 3;
                int k = kt * 32 + ((ll >> 4) << 3) + j, n = (nt << 4) + (ll & 15);
                base[rem] = f2bf(src[k * 128 + n]);
            }
        }
    }
}

// ---------------- K2b: scan of the 196 block sums (single block) ----------------
__global__ void k2b_scan2(int* bsums) {
    __shared__ int s[256];
    int t = threadIdx.x;
    int v = (t < SCAN_BLOCKS) ? bsums[t] : 0;
    s[t] = v;
    __syncthreads();
    for (int off = 1; off < 256; off <<= 1) {
        int u = (t >= off) ? s[t - off] : 0;
        __syncthreads();
        s[t] += u;
        __syncthreads();
    }
    if (t < SCAN_BLOCKS) bsums[t] = s[t] - v;
}

// ---------------- K3a: atomic-free scatter, packed 8B writes ----------------
__global__ void k3a_scatter(const int* __restrict__ rowp, const int* __restrict__ colp,
                            const int* __restrict__ ex, const int* __restrict__ bsums,
                            const int* __restrict__ rank, int2* __restrict__ rc_sorted) {
    int e = blockIdx.x * 256 + threadIdx.x;
    if (e >= N_EDGES) return;
    int c = colp[e];
    int pos = ex[c] + bsums[c >> 8] + rank[e];
    rc_sorted[pos] = make_int2(rowp[e], c);
}

// ---------------- K3b: encoder + S/D layer 0 ----------------
__global__ __launch_bounds__(256, 4) void k3b_encoder_sd(
    const float* __restrict__ x, const float* __restrict__ enc_w, const float* __restrict__ enc_b,
    const unsigned short* __restrict__ w1c, unsigned short* __restrict__ h,
    unsigned short* __restrict__ S, unsigned short* __restrict__ D)
{
    __shared__ float wts[NODE_IN * HID];
    __shared__ float bts[HID];
    __shared__ float xs[64][NODE_IN];
    __shared__ unsigned short hs[64][136];
    int t = threadIdx.x, wave = t >> 6, l = t & 63, q = l >> 4, l16 = l & 15;
    int n0 = blockIdx.x * 64;
    int nt0s = wave * 4;

    for (int i = t; i < NODE_IN * HID; i += 256) wts[i] = enc_w[i];
    if (t < HID) bts[t] = enc_b[t];
    for (int i = t; i < 64 * NODE_IN; i += 256) {
        int nl = i >> 4, ii = i & 15;
        int n = n0 + nl;
        xs[nl][ii] = (n < N_NODES) ? x[n * NODE_IN + ii] : 0.f;
    }
    short8 wr[4][4];
    #pragma unroll
    for (int kt = 0; kt < 4; kt++)
        #pragma unroll
        for (int i = 0; i < 4; i++)
            wr[kt][i] = *(const short8*)(w1c + ((kt * 16 + nt0s + i) * 64 + l) * 8);
    __syncthreads();

    for (int o = t; o < 64 * HID; o += 256) {
        int nl = o >> 7, cc = o & 127;
        float acc = bts[cc];
        #pragma unroll
        for (int i = 0; i < NODE_IN; i++) acc += xs[nl][i] * wts[i * HID + cc];
        unsigned short hb = f2bf(acc);
        hs[nl][cc] = hb;
        int n = n0 + nl;
        if (n < N_NODES) h[n * HID + cc] = hb;
    }
    __syncthreads();

    f32x4 acc[4][4];
    #pragma unroll
    for (int g = 0; g < 4; g++)
        #pragma unroll
        for (int i = 0; i < 4; i++) acc[g][i] = (f32x4){0.f, 0.f, 0.f, 0.f};
    #pragma unroll
    for (int kt = 0; kt < 4; kt++) {
        #pragma unroll
        for (int g = 0; g < 4; g++) {
            short8 a = *(const short8*)&hs[g * 16 + l16][kt * 32 + q * 8];
            #pragma unroll
            for (int i = 0; i < 4; i++)
                acc[g][i] = __builtin_amdgcn_mfma_f32_16x16x32_bf16(a, wr[kt][i], acc[g][i], 0, 0, 0);
        }
    }
    #pragma unroll
    for (int i = 0; i < 4; i++) {
        int cc = (nt0s + i) * 16 + l16;
        #pragma unroll
        for (int g = 0; g < 4; g++)
            #pragma unroll
            for (int r = 0; r < 4; r++) {
                int n = n0 + g * 16 + q * 4 + r;
                if (n < N_NODES) {
                    unsigned short v = f2bf(acc[g][i][r]);
                    if (cc < 128) S[n * HID + cc] = v;
                    else          D[n * HID + (cc - 128)] = v;
                }
            }
    }
}

// ---------------- edge: gather + relu + fp32 segreduce (2 barriers/tile) ----------------
__global__ __launch_bounds__(256, 4) void edge_kernel(
    const unsigned short* __restrict__ S, const unsigned short* __restrict__ D,
    const int2* __restrict__ rc_sorted,
    const float* __restrict__ b1, float* __restrict__ aggH)
{
    __shared__ float hid_s[64][132];
    __shared__ int col_s[64];
    int t = threadIdx.x;
    int ch = t & 15, eg = t >> 4;

    float b1v[8];
    #pragma unroll
    for (int j = 0; j < 8; j++) b1v[j] = b1[ch * 8 + j];

    for (int tile = blockIdx.x; tile < EDGE_TILES; tile += gridDim.x) {
        int e0 = tile * 64;

        // gather: each thread loads its own rc pairs (L1-broadcast across the
        // 16 threads sharing an edge); ch==0 lane publishes col_s.
        #pragma unroll
        for (int it = 0; it < 4; it++) {
            int el = it * 16 + eg;
            int2 rc = rc_sorted[e0 + el];
            if (ch == 0) col_s[el] = rc.y;
            short8 sv = *(const short8*)(S + (size_t)rc.x * HID + ch * 8);
            short8 dv = *(const short8*)(D + (size_t)rc.y * HID + ch * 8);
            float o[8];
            #pragma unroll
            for (int p = 0; p < 4; p++) {
                unsigned int us = ((const unsigned int*)&sv)[p];
                unsigned int ud = ((const unsigned int*)&dv)[p];
                float v0 = bfu_lo(us) + bfu_lo(ud) + b1v[p * 2];
                float v1 = bfu_hi(us) + bfu_hi(ud) + b1v[p * 2 + 1];
                o[p * 2]     = v0 > 0.f ? v0 : 0.f;
                o[p * 2 + 1] = v1 > 0.f ? v1 : 0.f;
            }
            *(f32x4*)&hid_s[el][ch * 8]     = *(f32x4*)&o[0];
            *(f32x4*)&hid_s[el][ch * 8 + 4] = *(f32x4*)&o[4];
        }
        __syncthreads();   // hid_s + col_s complete

        {
            int c = t & 127;
            int h2 = t >> 7;
            int r0 = h2 * 32;
            float accv = 0.f;
            int cur = col_s[r0];
            #pragma unroll 4
            for (int r = r0; r < r0 + 32; r++) {
                accv += hid_s[r][c];
                int nxt = (r == r0 + 31) ? -1 : col_s[r + 1];
                if (nxt != cur) {
                    unsafeAtomicAdd(&aggH[cur * HID + c], accv);
                    accv = 0.f;
                    cur = nxt;
                }
            }
        }
        __syncthreads();   // protect hid_s/col_s before next tile
    }
}

// ---------------- node MLP (folded GEMM1) + residual + (next S/D | decoder) ----------------
template<int LAST>
__global__ __launch_bounds__(256, 4) void node_kernel(
    unsigned short* __restrict__ h, float* __restrict__ aggH, const int* __restrict__ cnt,
    const unsigned short* __restrict__ w1m_s, const float* __restrict__ b1,
    const float* __restrict__ vfold,
    const unsigned short* __restrict__ w2s, const float* __restrict__ b2,
    const unsigned short* __restrict__ w1c_next,
    unsigned short* __restrict__ S, unsigned short* __restrict__ D,
    const float* __restrict__ dec_w, const float* __restrict__ dec_b, float* __restrict__ out)
{
    __shared__ unsigned short in_h[64][136];   // old h -> new h after residual
    __shared__ unsigned short in_a[64][136];   // bf16(aggH); reused as hid after GEMM1
    __shared__ int cnt_s[64];
    __shared__ float dw[HID * NODE_OUT];
    __shared__ float db[NODE_OUT];
    int t = threadIdx.x, wave = t >> 6, l = t & 63, q = l >> 4, l16 = l & 15;
    int nt0 = wave * 2, nt0s = wave * 4;
    int n0 = blockIdx.x * 64;

    if (LAST) {
        for (int i = t; i < HID * NODE_OUT; i += 256) dw[i] = dec_w[i];
        if (t < NODE_OUT) db[t] = dec_b[t];
    }

    // stage: h -> in_h, bf16(aggH) -> in_a (re-zero aggH for next layer), cnt
    #pragma unroll
    for (int it = 0; it < 8; it++) {
        int g = it * 256 + t;
        int nl = g >> 5, sub = g & 31, half = sub >> 4, li = sub & 15;
        int n = n0 + nl;
        short8 v = (short8){0, 0, 0, 0, 0, 0, 0, 0};
        if (n < N_NODES) {
            if (half == 0) {
                v = *(const short8*)(h + n * HID + li * 8);
            } else {
                float* ap = aggH + n * HID + li * 8;
                f32x4 a0 = *(f32x4*)ap, a1 = *(f32x4*)(ap + 4);
                #pragma unroll
                for (int j = 0; j < 4; j++) {
                    ((unsigned short*)&v)[j]     = f2bf(a0[j]);
                    ((unsigned short*)&v)[4 + j] = f2bf(a1[j]);
                }
                if (!LAST) {
                    *(f32x4*)ap       = (f32x4){0.f, 0.f, 0.f, 0.f};
                    *(f32x4*)(ap + 4) = (f32x4){0.f, 0.f, 0.f, 0.f};
                }
            }
        }
        if (half == 0) *(short8*)&in_h[nl][li * 8] = v;
        else           *(short8*)&in_a[nl][li * 8] = v;
    }
    if (t < 64) cnt_s[t] = (n0 + t < N_NODES) ? cnt[n0 + t] : 0;
    __syncthreads();

    float b1r0 = b1[nt0 * 16 + l16], b1r1 = b1[(nt0 + 1) * 16 + l16];
    float vr0 = vfold[nt0 * 16 + l16], vr1 = vfold[(nt0 + 1) * 16 + l16];
    float b2r0 = b2[nt0 * 16 + l16], b2r1 = b2[(nt0 + 1) * 16 + l16];

    // GEMM1 (K=256, B = [W1top; M] folded): h@W1top + aggH@M
    f32x4 acc[4][2];
    #pragma unroll
    for (int g = 0; g < 4; g++)
        #pragma unroll
        for (int j = 0; j < 2; j++) acc[g][j] = (f32x4){0.f, 0.f, 0.f, 0.f};
    #pragma unroll
    for (int kt = 0; kt < 8; kt++) {
        short8 b0 = *(const short8*)(w1m_s + ((kt * 8 + nt0)     * 64 + l) * 8);
        short8 b1v = *(const short8*)(w1m_s + ((kt * 8 + nt0 + 1) * 64 + l) * 8);
        #pragma unroll
        for (int g = 0; g < 4; g++) {
            short8 a = (kt < 4) ? *(const short8*)&in_h[g * 16 + l16][kt * 32 + q * 8]
                                : *(const short8*)&in_a[g * 16 + l16][(kt - 4) * 32 + q * 8];
            acc[g][0] = __builtin_amdgcn_mfma_f32_16x16x32_bf16(a, b0, acc[g][0], 0, 0, 0);
            acc[g][1] = __builtin_amdgcn_mfma_f32_16x16x32_bf16(a, b1v, acc[g][1], 0, 0, 0);
        }
    }
    __syncthreads();   // all in_a reads complete before hid overwrite

    // epilogue: + b1 + deg*v -> relu -> hid (aliases in_a)
    #pragma unroll
    for (int j = 0; j < 2; j++) {
        float bv = j ? b1r1 : b1r0;
        float vv = j ? vr1 : vr0;
        #pragma unroll
        for (int g = 0; g < 4; g++)
            #pragma unroll
            for (int r = 0; r < 4; r++) {
                int m2 = g * 16 + q * 4 + r;
                float v = acc[g][j][r] + bv + (float)cnt_s[m2] * vv;
                v = v > 0.f ? v : 0.f;
                in_a[m2][(nt0 + j) * 16 + l16] = f2bf(v);
            }
    }
    __syncthreads();

    // GEMM2n (K=128) -> residual -> h + in_h
    f32x4 acc2[4][2];
    #pragma unroll
    for (int g = 0; g < 4; g++)
        #pragma unroll
        for (int j = 0; j < 2; j++) acc2[g][j] = (f32x4){0.f, 0.f, 0.f, 0.f};
    #pragma unroll
    for (int kt = 0; kt < 4; kt++) {
        short8 b0 = *(const short8*)(w2s + ((kt * 8 + nt0)     * 64 + l) * 8);
        short8 b1v = *(const short8*)(w2s + ((kt * 8 + nt0 + 1) * 64 + l) * 8);
        #pragma unroll
        for (int g = 0; g < 4; g++) {
            short8 a = *(const short8*)&in_a[g * 16 + l16][kt * 32 + q * 8];
            acc2[g][0] = __builtin_amdgcn_mfma_f32_16x16x32_bf16(a, b0, acc2[g][0], 0, 0, 0);
            acc2[g][1] = __builtin_amdgcn_mfma_f32_16x16x32_bf16(a, b1v, acc2[g][1], 0, 0, 0);
        }
    }
    #pragma unroll
    for (int j = 0; j < 2; j++) {
        float bv = j ? b2r1 : b2r0;
        #pragma unroll
        for (int g = 0; g < 4; g++)
            #pragma unroll
            for (int r = 0; r < 4; r++) {
                float v = acc2[g][j][r] + bv;
                int m2 = g * 16 + q * 4 + r;
                int n = n0 + m2;
                if (n < N_NODES) {
                    int c = (nt0 + j) * 16 + l16;
                    unsigned short nh = f2bf(bf2f(in_h[m2][c]) + v);   // residual (same-thread cell)
                    if (!LAST) h[n * HID + c] = nh;
                    in_h[m2][c] = nh;
                }
            }
    }
    __syncthreads();

    if (!LAST) {
        // next-layer S/D from new h (in_h), in 2 register-light passes
        #pragma unroll
        for (int p = 0; p < 2; p++) {
            short8 wr[4][2];
            #pragma unroll
            for (int kt = 0; kt < 4; kt++) {
                wr[kt][0] = *(const short8*)(w1c_next + ((kt * 16 + nt0s + p * 2)     * 64 + l) * 8);
                wr[kt][1] = *(const short8*)(w1c_next + ((kt * 16 + nt0s + p * 2 + 1) * 64 + l) * 8);
            }
            f32x4 accs[4][2];
            #pragma unroll
            for (int g = 0; g < 4; g++)
                #pragma unroll
                for (int i = 0; i < 2; i++) accs[g][i] = (f32x4){0.f, 0.f, 0.f, 0.f};
            #pragma unroll
            for (int kt = 0; kt < 4; kt++) {
                #pragma unroll
                for (int g = 0; g < 4; g++) {
                    short8 a = *(const short8*)&in_h[g * 16 + l16][kt * 32 + q * 8];
                    accs[g][0] = __builtin_amdgcn_mfma_f32_16x16x32_bf16(a, wr[kt][0], accs[g][0], 0, 0, 0);
                    accs[g][1] = __builtin_amdgcn_mfma_f32_16x16x32_bf16(a, wr[kt][1], accs[g][1], 0, 0, 0);
                }
            }
            #pragma unroll
            for (int i = 0; i < 2; i++) {
                int c = (nt0s + p * 2 + i) * 16 + l16;
                #pragma unroll
                for (int g = 0; g < 4; g++)
                    #pragma unroll
                    for (int r = 0; r < 4; r++) {
                        int n = n0 + g * 16 + q * 4 + r;
                        if (n < N_NODES) {
                            unsigned short v = f2bf(accs[g][i][r]);
                            if (c < 128) S[n * HID + c] = v;
                            else         D[n * HID + (c - 128)] = v;
                        }
                    }
            }
        }
    } else {
        // decoder: out = new_h @ dec_w + dec_b
        if (t < 64 * NODE_OUT) {
            int nl = t / 3, o = t - 3 * nl;
            int n = n0 + nl;
            if (n < N_NODES) {
                float a = db[o];
                #pragma unroll 4
                for (int k = 0; k < HID; k++) a += bf2f(in_h[nl][k]) * dw[k * 3 + o];
                out[n * 3 + o] = a;
            }
        }
    }
}

extern "C" void kernel_launch(void* const* d_in, const int* in_sizes, int n_in,
                              void* d_out, int out_size, void* d_ws, size_t ws_size,
                              hipStream_t stream) {
    const float* x       = (const float*)d_in[0];
    const int*   ei      = (const int*)d_in[1];
    const float* enc_w   = (const float*)d_in[2];
    const float* enc_b   = (const float*)d_in[3];
    const float* dec_w   = (const float*)d_in[4];
    const float* dec_b   = (const float*)d_in[5];
    const float* edge_w1 = (const float*)d_in[6];
    const float* edge_b1 = (const float*)d_in[7];
    const float* edge_w2 = (const float*)d_in[8];
    const float* edge_b2 = (const float*)d_in[9];
    const float* node_w1 = (const float*)d_in[10];
    const float* node_b1 = (const float*)d_in[11];
    const float* node_w2 = (const float*)d_in[12];
    const float* node_b2 = (const float*)d_in[13];

    char* ws = (char*)d_ws;
    unsigned short* h    = (unsigned short*)ws;                    // 12.8 MB
    float*          aggH = (float*)(ws + 12800000);                // 25.6 MB
    unsigned short* swz  = (unsigned short*)(ws + 38400000);       // 589,824 B
    int* cnt             = (int*)(ws + 38989824);                  // 200,000 B (degrees)
    int* ex              = (int*)(ws + 39189824);                  // 200,000 B
    int* bsums           = (int*)(ws + 39389824);                  // 1,024 B
    int2* rc_sorted      = (int2*)(ws + 39390848);                 // 6.4 MB
    unsigned short* Sbuf = (unsigned short*)(ws + 45790848);       // 12.8 MB
    unsigned short* Dbuf = (unsigned short*)(ws + 58590848);       // 12.8 MB
    float* Mtmp          = (float*)(ws + 71390848);                // 196,608 B
    float* Vtmp          = (float*)(ws + 71587456);                // 1,536 B -> end 71,588,992
    // rank overlays the Dbuf region: written in k1, consumed in k3a,
    // before Dbuf's first write in k3b. No extra workspace.
    int* rank            = (int*)(ws + 58590848);                  // 3.2 MB (aliases Dbuf)

    const int* rowp = ei;            // edge_index[0] = source
    const int* colp = ei + N_EDGES;  // edge_index[1] = destination

    hipMemsetAsync(cnt, 0, (size_t)N_NODES * 4, stream);
    hipMemsetAsync(aggH, 0, (size_t)N_NODES * HID * 4, stream);    // layer-0 aggH zero

    k1_hist_mfold<<<1024, 256, 0, stream>>>(colp, cnt, rank, edge_w2, node_w1, edge_b2,
                                            Mtmp, Vtmp);
    k2a_scan1_swizzle<<<SCAN_BLOCKS + 288, 256, 0, stream>>>(cnt, ex, bsums, edge_w1,
                                                             node_w1, node_w2, Mtmp, swz);
    k2b_scan2<<<1, 256, 0, stream>>>(bsums);
    k3a_scatter<<<3125, 256, 0, stream>>>(rowp, colp, ex, bsums, rank, rc_sorted);
    k3b_encoder_sd<<<NODE_TILES, 256, 0, stream>>>(x, enc_w, enc_b, swz /*L0 w1cat*/, h,
                                                   Sbuf, Dbuf);

    for (int L = 0; L < 3; L++) {
        unsigned short* base = swz + (size_t)L * 98304;
        unsigned short* next = swz + (size_t)(L + 1) * 98304;   // w1cat of next layer
        edge_kernel<<<1024, 256, 0, stream>>>(Sbuf, Dbuf, rc_sorted,
                                              edge_b1 + (size_t)L * HID, aggH);
        if (L < 2) {
            node_kernel<0><<<NODE_TILES, 256, 0, stream>>>(
                h, aggH, cnt,
                base + 49152, node_b1 + (size_t)L * HID, Vtmp + (size_t)L * HID,
                base + 81920, node_b2 + (size_t)L * HID,
                next, Sbuf, Dbuf, dec_w, dec_b, (float*)d_out);
        } else {
            node_kernel<1><<<NODE_TILES, 256, 0, stream>>>(
                h, aggH, cnt,
                base + 49152, node_b1 + (size_t)L * HID, Vtmp + (size_t)L * HID,
                base + 81920, node_b2 + (size_t)L * HID,
                base /*unused*/, Sbuf, Dbuf, dec_w, dec_b, (float*)d_out);
        }
    }
}

// Round 16
// 405.508 us; speedup vs baseline: 2.6601x; 1.0845x over previous
//
#include <hip/hip_runtime.h>
#include <hip/hip_bf16.h>
#include <stdint.h>

#define N_NODES 50000
#define N_EDGES 800000
#define HID 128
#define NODE_IN 16
#define NODE_OUT 3
#define EDGE_TILES 12500   // 800000 / 64
#define NODE_TILES 782     // ceil(50000 / 64)
#define SCAN_BLOCKS 196    // ceil(50000 / 256)

typedef __attribute__((ext_vector_type(8))) short short8;
typedef __attribute__((ext_vector_type(4))) float f32x4;

__device__ __forceinline__ unsigned short f2bf(float f) {
    union { float f; unsigned int u; } v; v.f = f;
    unsigned int u = v.u;
    u += 0x7fff + ((u >> 16) & 1);   // round-to-nearest-even
    return (unsigned short)(u >> 16);
}
__device__ __forceinline__ float bf2f(unsigned short s) {
    union { unsigned int u; float f; } v; v.u = ((unsigned int)s) << 16;
    return v.f;
}
__device__ __forceinline__ float bfu_lo(unsigned int u) {
    union { unsigned int u; float f; } v; v.u = u << 16; return v.f;
}
__device__ __forceinline__ float bfu_hi(unsigned int u) {
    union { unsigned int u; float f; } v; v.u = u & 0xffff0000u; return v.f;
}

// ---------------- K1: degree histogram (+ per-edge rank) + M-fold ----------------
__global__ void k1_hist_mfold(const int* __restrict__ colp, int* __restrict__ cnt,
                              int* __restrict__ rank,
                              const float* __restrict__ edge_w2, const float* __restrict__ node_w1,
                              const float* __restrict__ edge_b2,
                              float* __restrict__ Mtmp, float* __restrict__ Vtmp) {
    for (int e = blockIdx.x * 256 + threadIdx.x; e < N_EDGES; e += gridDim.x * 256)
        rank[e] = atomicAdd(&cnt[colp[e]], 1);   // old value = within-dest rank
    for (int d = blockIdx.x * 256 + threadIdx.x; d < 3 * 16384; d += gridDim.x * 256) {
        int L = d / 16384, rem = d & 16383;
        int k = rem >> 7, n = rem & 127;
        const float* w2  = edge_w2 + (size_t)L * 16384;
        const float* w1b = node_w1 + (size_t)L * 32768 + 16384;   // bottom-half rows
        float acc = 0.f;
        #pragma unroll 4
        for (int j = 0; j < 128; j++) acc += w2[k * 128 + j] * w1b[j * 128 + n];
        Mtmp[d] = acc;
        if (k == 0) {
            const float* b2 = edge_b2 + (size_t)L * 128;
            float vv = 0.f;
            #pragma unroll 4
            for (int j = 0; j < 128; j++) vv += b2[j] * w1b[j * 128 + n];
            Vtmp[L * 128 + n] = vv;
        }
    }
}

// ---------------- K2a: parallel scan1 (blocks < SCAN_BLOCKS) + weight swizzles ----------------
// swz per-layer layout: +0 edge w1cat (32768), [32768..49152) unused,
//                       +49152 node w1-modified [W1top; M] (32768), +81920 node w2 (16384)
__global__ __launch_bounds__(256) void k2a_scan1_swizzle(
    const int* __restrict__ cnt, int* __restrict__ ex, int* __restrict__ bsums,
    const float* __restrict__ edge_w1, const float* __restrict__ node_w1,
    const float* __restrict__ node_w2, const float* __restrict__ Mtmp,
    unsigned short* __restrict__ swz) {
    __shared__ int s[256];
    int b = blockIdx.x, t = threadIdx.x;
    if (b < SCAN_BLOCKS) {
        int i = b * 256 + t;
        int v = (i < N_NODES) ? cnt[i] : 0;
        s[t] = v;
        __syncthreads();
        for (int off = 1; off < 256; off <<= 1) {
            int u = (t >= off) ? s[t - off] : 0;
            __syncthreads();
            s[t] += u;
            __syncthreads();
        }
        if (i < N_NODES) ex[i] = s[t] - v;
        if (t == 255) bsums[b] = s[255];
    } else {
        for (int d = (b - SCAN_BLOCKS) * 256 + t; d < 3 * 98304;
             d += (gridDim.x - SCAN_BLOCKS) * 256) {
            int L = d / 98304;
            int rem = d - L * 98304;
            unsigned short* base = swz + L * 98304;
            if (rem < 32768) {
                // edge w1 combined [128 x 256] B-frags (16 n-tiles)
                const float* w1 = edge_w1 + (size_t)L * 32768;
                int j = rem & 7, ll = (rem >> 3) & 63, tt = rem >> 9;
                int nt = tt & 15, kt = tt >> 4;
                int k = kt * 32 + ((ll >> 4) << 3) + j;
                int cc = nt * 16 + (ll & 15);
                float v = (cc < 128) ? w1[k * 128 + cc] : w1[(128 + k) * 128 + (cc - 128)];
                base[rem] = f2bf(v);
            } else if (rem < 49152) {
                // unused slot (edge w2 folded into node w1 via M)
            } else if (rem < 81920) {
                int d2 = rem - 49152;
                int j = d2 & 7, ll = (d2 >> 3) & 63, tt = d2 >> 9;
                int nt = tt & 7, kt = tt >> 3;
                int k = kt * 32 + ((ll >> 4) << 3) + j, n = (nt << 4) + (ll & 15);
                float v = (k < 128) ? node_w1[(size_t)L * 32768 + k * 128 + n]
                                    : Mtmp[(size_t)L * 16384 + (k - 128) * 128 + n];
                base[rem] = f2bf(v);
            } else {
                int d2 = rem - 81920;
                const float* src = node_w2 + (size_t)L * 16384;
                int j = d2 & 7, ll = (d2 >> 3) & 63, tt = d2 >> 9;
                int nt = tt & 7, kt = tt >> 3;
                int k = kt * 32 + ((ll >> 4) << 3) + j, n = (nt << 4) + (ll & 15);
                base[rem] = f2bf(src[k * 128 + n]);
            }
        }
    }
}

// ---------------- K2b: scan of the 196 block sums (single block) ----------------
__global__ void k2b_scan2(int* bsums) {
    __shared__ int s[256];
    int t = threadIdx.x;
    int v = (t < SCAN_BLOCKS) ? bsums[t] : 0;
    s[t] = v;
    __syncthreads();
    for (int off = 1; off < 256; off <<= 1) {
        int u = (t >= off) ? s[t - off] : 0;
        __syncthreads();
        s[t] += u;
        __syncthreads();
    }
    if (t < SCAN_BLOCKS) bsums[t] = s[t] - v;
}

// ---------------- K3a: atomic-free scatter, packed 8B writes ----------------
__global__ void k3a_scatter(const int* __restrict__ rowp, const int* __restrict__ colp,
                            const int* __restrict__ ex, const int* __restrict__ bsums,
                            const int* __restrict__ rank, int2* __restrict__ rc_sorted) {
    int e = blockIdx.x * 256 + threadIdx.x;
    if (e >= N_EDGES) return;
    int c = colp[e];
    int pos = ex[c] + bsums[c >> 8] + rank[e];
    rc_sorted[pos] = make_int2(rowp[e], c);
}

// ---------------- K3b: encoder + S/D layer 0 ----------------
__global__ __launch_bounds__(256, 4) void k3b_encoder_sd(
    const float* __restrict__ x, const float* __restrict__ enc_w, const float* __restrict__ enc_b,
    const unsigned short* __restrict__ w1c, unsigned short* __restrict__ h,
    unsigned short* __restrict__ S, unsigned short* __restrict__ D)
{
    __shared__ float wts[NODE_IN * HID];
    __shared__ float bts[HID];
    __shared__ float xs[64][NODE_IN];
    __shared__ unsigned short hs[64][136];
    int t = threadIdx.x, wave = t >> 6, l = t & 63, q = l >> 4, l16 = l & 15;
    int n0 = blockIdx.x * 64;
    int nt0s = wave * 4;

    for (int i = t; i < NODE_IN * HID; i += 256) wts[i] = enc_w[i];
    if (t < HID) bts[t] = enc_b[t];
    for (int i = t; i < 64 * NODE_IN; i += 256) {
        int nl = i >> 4, ii = i & 15;
        int n = n0 + nl;
        xs[nl][ii] = (n < N_NODES) ? x[n * NODE_IN + ii] : 0.f;
    }
    short8 wr[4][4];
    #pragma unroll
    for (int kt = 0; kt < 4; kt++)
        #pragma unroll
        for (int i = 0; i < 4; i++)
            wr[kt][i] = *(const short8*)(w1c + ((kt * 16 + nt0s + i) * 64 + l) * 8);
    __syncthreads();

    for (int o = t; o < 64 * HID; o += 256) {
        int nl = o >> 7, cc = o & 127;
        float acc = bts[cc];
        #pragma unroll
        for (int i = 0; i < NODE_IN; i++) acc += xs[nl][i] * wts[i * HID + cc];
        unsigned short hb = f2bf(acc);
        hs[nl][cc] = hb;
        int n = n0 + nl;
        if (n < N_NODES) h[n * HID + cc] = hb;
    }
    __syncthreads();

    f32x4 acc[4][4];
    #pragma unroll
    for (int g = 0; g < 4; g++)
        #pragma unroll
        for (int i = 0; i < 4; i++) acc[g][i] = (f32x4){0.f, 0.f, 0.f, 0.f};
    #pragma unroll
    for (int kt = 0; kt < 4; kt++) {
        #pragma unroll
        for (int g = 0; g < 4; g++) {
            short8 a = *(const short8*)&hs[g * 16 + l16][kt * 32 + q * 8];
            #pragma unroll
            for (int i = 0; i < 4; i++)
                acc[g][i] = __builtin_amdgcn_mfma_f32_16x16x32_bf16(a, wr[kt][i], acc[g][i], 0, 0, 0);
        }
    }
    #pragma unroll
    for (int i = 0; i < 4; i++) {
        int cc = (nt0s + i) * 16 + l16;
        #pragma unroll
        for (int g = 0; g < 4; g++)
            #pragma unroll
            for (int r = 0; r < 4; r++) {
                int n = n0 + g * 16 + q * 4 + r;
                if (n < N_NODES) {
                    unsigned short v = f2bf(acc[g][i][r]);
                    if (cc < 128) S[n * HID + cc] = v;
                    else          D[n * HID + (cc - 128)] = v;
                }
            }
    }
}

// ---------------- edge: staged gather + relu(bf16 LDS) + fp32 segreduce ----------------
// Round-13 3-barrier structure; hid_s in bf16 -> 17.9 KB LDS -> 8 blocks/CU.
__global__ __launch_bounds__(256, 8) void edge_kernel(
    const unsigned short* __restrict__ S, const unsigned short* __restrict__ D,
    const int2* __restrict__ rc_sorted,
    const float* __restrict__ b1, float* __restrict__ aggH)
{
    __shared__ unsigned short hid_s[64][136];   // bf16 relu outputs, 17,408 B
    __shared__ int row_s[64], col_s[64];        //    512 B
    int t = threadIdx.x;
    int ch = t & 15;

    float b1v[8];
    #pragma unroll
    for (int j = 0; j < 8; j++) b1v[j] = b1[ch * 8 + j];

    for (int tile = blockIdx.x; tile < EDGE_TILES; tile += gridDim.x) {
        int e0 = tile * 64;
        if (t < 64) {
            int2 rc = rc_sorted[e0 + t];
            row_s[t] = rc.x;
            col_s[t] = rc.y;
        }
        __syncthreads();

        #pragma unroll
        for (int it = 0; it < 4; it++) {
            int el = it * 16 + (t >> 4);
            int r = row_s[el], c = col_s[el];
            short8 sv = *(const short8*)(S + (size_t)r * HID + ch * 8);
            short8 dv = *(const short8*)(D + (size_t)c * HID + ch * 8);
            short8 o;
            #pragma unroll
            for (int p = 0; p < 4; p++) {
                unsigned int us = ((const unsigned int*)&sv)[p];
                unsigned int ud = ((const unsigned int*)&dv)[p];
                float v0 = bfu_lo(us) + bfu_lo(ud) + b1v[p * 2];
                float v1 = bfu_hi(us) + bfu_hi(ud) + b1v[p * 2 + 1];
                ((unsigned short*)&o)[p * 2]     = f2bf(v0 > 0.f ? v0 : 0.f);
                ((unsigned short*)&o)[p * 2 + 1] = f2bf(v1 > 0.f ? v1 : 0.f);
            }
            *(short8*)&hid_s[el][ch * 8] = o;
        }
        __syncthreads();

        {
            int c = t & 127;
            int h2 = t >> 7;
            int r0 = h2 * 32;
            float accv = 0.f;
            int cur = col_s[r0];
            #pragma unroll 4
            for (int r = r0; r < r0 + 32; r++) {
                accv += bf2f(hid_s[r][c]);
                int nxt = (r == r0 + 31) ? -1 : col_s[r + 1];
                if (nxt != cur) {
                    unsafeAtomicAdd(&aggH[cur * HID + c], accv);
                    accv = 0.f;
                    cur = nxt;
                }
            }
        }
        __syncthreads();
    }
}

// ---------------- node MLP (folded GEMM1) + residual + (next S/D | decoder) ----------------
template<int LAST>
__global__ __launch_bounds__(256, 4) void node_kernel(
    unsigned short* __restrict__ h, float* __restrict__ aggH, const int* __restrict__ cnt,
    const unsigned short* __restrict__ w1m_s, const float* __restrict__ b1,
    const float* __restrict__ vfold,
    const unsigned short* __restrict__ w2s, const float* __restrict__ b2,
    const unsigned short* __restrict__ w1c_next,
    unsigned short* __restrict__ S, unsigned short* __restrict__ D,
    const float* __restrict__ dec_w, const float* __restrict__ dec_b, float* __restrict__ out)
{
    __shared__ unsigned short in_h[64][136];   // old h -> new h after residual
    __shared__ unsigned short in_a[64][136];   // bf16(aggH); reused as hid after GEMM1
    __shared__ int cnt_s[64];
    __shared__ float dw[HID * NODE_OUT];
    __shared__ float db[NODE_OUT];
    int t = threadIdx.x, wave = t >> 6, l = t & 63, q = l >> 4, l16 = l & 15;
    int nt0 = wave * 2, nt0s = wave * 4;
    int n0 = blockIdx.x * 64;

    if (LAST) {
        for (int i = t; i < HID * NODE_OUT; i += 256) dw[i] = dec_w[i];
        if (t < NODE_OUT) db[t] = dec_b[t];
    }

    // stage: h -> in_h, bf16(aggH) -> in_a (re-zero aggH for next layer), cnt
    #pragma unroll
    for (int it = 0; it < 8; it++) {
        int g = it * 256 + t;
        int nl = g >> 5, sub = g & 31, half = sub >> 4, li = sub & 15;
        int n = n0 + nl;
        short8 v = (short8){0, 0, 0, 0, 0, 0, 0, 0};
        if (n < N_NODES) {
            if (half == 0) {
                v = *(const short8*)(h + n * HID + li * 8);
            } else {
                float* ap = aggH + n * HID + li * 8;
                f32x4 a0 = *(f32x4*)ap, a1 = *(f32x4*)(ap + 4);
                #pragma unroll
                for (int j = 0; j < 4; j++) {
                    ((unsigned short*)&v)[j]     = f2bf(a0[j]);
                    ((unsigned short*)&v)[4 + j] = f2bf(a1[j]);
                }
                if (!LAST) {
                    *(f32x4*)ap       = (f32x4){0.f, 0.f, 0.f, 0.f};
                    *(f32x4*)(ap + 4) = (f32x4){0.f, 0.f, 0.f, 0.f};
                }
            }
        }
        if (half == 0) *(short8*)&in_h[nl][li * 8] = v;
        else           *(short8*)&in_a[nl][li * 8] = v;
    }
    if (t < 64) cnt_s[t] = (n0 + t < N_NODES) ? cnt[n0 + t] : 0;
    __syncthreads();

    float b1r0 = b1[nt0 * 16 + l16], b1r1 = b1[(nt0 + 1) * 16 + l16];
    float vr0 = vfold[nt0 * 16 + l16], vr1 = vfold[(nt0 + 1) * 16 + l16];
    float b2r0 = b2[nt0 * 16 + l16], b2r1 = b2[(nt0 + 1) * 16 + l16];

    // GEMM1 (K=256, B = [W1top; M] folded): h@W1top + aggH@M
    f32x4 acc[4][2];
    #pragma unroll
    for (int g = 0; g < 4; g++)
        #pragma unroll
        for (int j = 0; j < 2; j++) acc[g][j] = (f32x4){0.f, 0.f, 0.f, 0.f};
    #pragma unroll
    for (int kt = 0; kt < 8; kt++) {
        short8 b0 = *(const short8*)(w1m_s + ((kt * 8 + nt0)     * 64 + l) * 8);
        short8 b1v = *(const short8*)(w1m_s + ((kt * 8 + nt0 + 1) * 64 + l) * 8);
        #pragma unroll
        for (int g = 0; g < 4; g++) {
            short8 a = (kt < 4) ? *(const short8*)&in_h[g * 16 + l16][kt * 32 + q * 8]
                                : *(const short8*)&in_a[g * 16 + l16][(kt - 4) * 32 + q * 8];
            acc[g][0] = __builtin_amdgcn_mfma_f32_16x16x32_bf16(a, b0, acc[g][0], 0, 0, 0);
            acc[g][1] = __builtin_amdgcn_mfma_f32_16x16x32_bf16(a, b1v, acc[g][1], 0, 0, 0);
        }
    }
    __syncthreads();   // all in_a reads complete before hid overwrite

    // epilogue: + b1 + deg*v -> relu -> hid (aliases in_a)
    #pragma unroll
    for (int j = 0; j < 2; j++) {
        float bv = j ? b1r1 : b1r0;
        float vv = j ? vr1 : vr0;
        #pragma unroll
        for (int g = 0; g < 4; g++)
            #pragma unroll
            for (int r = 0; r < 4; r++) {
                int m2 = g * 16 + q * 4 + r;
                float v = acc[g][j][r] + bv + (float)cnt_s[m2] * vv;
                v = v > 0.f ? v : 0.f;
                in_a[m2][(nt0 + j) * 16 + l16] = f2bf(v);
            }
    }
    __syncthreads();

    // GEMM2n (K=128) -> residual -> h + in_h
    f32x4 acc2[4][2];
    #pragma unroll
    for (int g = 0; g < 4; g++)
        #pragma unroll
        for (int j = 0; j < 2; j++) acc2[g][j] = (f32x4){0.f, 0.f, 0.f, 0.f};
    #pragma unroll
    for (int kt = 0; kt < 4; kt++) {
        short8 b0 = *(const short8*)(w2s + ((kt * 8 + nt0)     * 64 + l) * 8);
        short8 b1v = *(const short8*)(w2s + ((kt * 8 + nt0 + 1) * 64 + l) * 8);
        #pragma unroll
        for (int g = 0; g < 4; g++) {
            short8 a = *(const short8*)&in_a[g * 16 + l16][kt * 32 + q * 8];
            acc2[g][0] = __builtin_amdgcn_mfma_f32_16x16x32_bf16(a, b0, acc2[g][0], 0, 0, 0);
            acc2[g][1] = __builtin_amdgcn_mfma_f32_16x16x32_bf16(a, b1v, acc2[g][1], 0, 0, 0);
        }
    }
    #pragma unroll
    for (int j = 0; j < 2; j++) {
        float bv = j ? b2r1 : b2r0;
        #pragma unroll
        for (int g = 0; g < 4; g++)
            #pragma unroll
            for (int r = 0; r < 4; r++) {
                float v = acc2[g][j][r] + bv;
                int m2 = g * 16 + q * 4 + r;
                int n = n0 + m2;
                if (n < N_NODES) {
                    int c = (nt0 + j) * 16 + l16;
                    unsigned short nh = f2bf(bf2f(in_h[m2][c]) + v);   // residual (same-thread cell)
                    if (!LAST) h[n * HID + c] = nh;
                    in_h[m2][c] = nh;
                }
            }
    }
    __syncthreads();

    if (!LAST) {
        // next-layer S/D from new h (in_h), in 2 register-light passes
        #pragma unroll
        for (int p = 0; p < 2; p++) {
            short8 wr[4][2];
            #pragma unroll
            for (int kt = 0; kt < 4; kt++) {
                wr[kt][0] = *(const short8*)(w1c_next + ((kt * 16 + nt0s + p * 2)     * 64 + l) * 8);
                wr[kt][1] = *(const short8*)(w1c_next + ((kt * 16 + nt0s + p * 2 + 1) * 64 + l) * 8);
            }
            f32x4 accs[4][2];
            #pragma unroll
            for (int g = 0; g < 4; g++)
                #pragma unroll
                for (int i = 0; i < 2; i++) accs[g][i] = (f32x4){0.f, 0.f, 0.f, 0.f};
            #pragma unroll
            for (int kt = 0; kt < 4; kt++) {
                #pragma unroll
                for (int g = 0; g < 4; g++) {
                    short8 a = *(const short8*)&in_h[g * 16 + l16][kt * 32 + q * 8];
                    accs[g][0] = __builtin_amdgcn_mfma_f32_16x16x32_bf16(a, wr[kt][0], accs[g][0], 0, 0, 0);
                    accs[g][1] = __builtin_amdgcn_mfma_f32_16x16x32_bf16(a, wr[kt][1], accs[g][1], 0, 0, 0);
                }
            }
            #pragma unroll
            for (int i = 0; i < 2; i++) {
                int c = (nt0s + p * 2 + i) * 16 + l16;
                #pragma unroll
                for (int g = 0; g < 4; g++)
                    #pragma unroll
                    for (int r = 0; r < 4; r++) {
                        int n = n0 + g * 16 + q * 4 + r;
                        if (n < N_NODES) {
                            unsigned short v = f2bf(accs[g][i][r]);
                            if (c < 128) S[n * HID + c] = v;
                            else         D[n * HID + (c - 128)] = v;
                        }
                    }
            }
        }
    } else {
        // decoder: out = new_h @ dec_w + dec_b
        if (t < 64 * NODE_OUT) {
            int nl = t / 3, o = t - 3 * nl;
            int n = n0 + nl;
            if (n < N_NODES) {
                float a = db[o];
                #pragma unroll 4
                for (int k = 0; k < HID; k++) a += bf2f(in_h[nl][k]) * dw[k * 3 + o];
                out[n * 3 + o] = a;
            }
        }
    }
}

extern "C" void kernel_launch(void* const* d_in, const int* in_sizes, int n_in,
                              void* d_out, int out_size, void* d_ws, size_t ws_size,
                              hipStream_t stream) {
    const float* x       = (const float*)d_in[0];
    const int*   ei      = (const int*)d_in[1];
    const float* enc_w   = (const float*)d_in[2];
    const float* enc_b   = (const float*)d_in[3];
    const float* dec_w   = (const float*)d_in[4];
    const float* dec_b   = (const float*)d_in[5];
    const float* edge_w1 = (const float*)d_in[6];
    const float* edge_b1 = (const float*)d_in[7];
    const float* edge_w2 = (const float*)d_in[8];
    const float* edge_b2 = (const float*)d_in[9];
    const float* node_w1 = (const float*)d_in[10];
    const float* node_b1 = (const float*)d_in[11];
    const float* node_w2 = (const float*)d_in[12];
    const float* node_b2 = (const float*)d_in[13];

    char* ws = (char*)d_ws;
    unsigned short* h    = (unsigned short*)ws;                    // 12.8 MB
    float*          aggH = (float*)(ws + 12800000);                // 25.6 MB
    unsigned short* swz  = (unsigned short*)(ws + 38400000);       // 589,824 B
    int* cnt             = (int*)(ws + 38989824);                  // 200,000 B (degrees)
    int* ex              = (int*)(ws + 39189824);                  // 200,000 B
    int* bsums           = (int*)(ws + 39389824);                  // 1,024 B
    int2* rc_sorted      = (int2*)(ws + 39390848);                 // 6.4 MB
    unsigned short* Sbuf = (unsigned short*)(ws + 45790848);       // 12.8 MB
    unsigned short* Dbuf = (unsigned short*)(ws + 58590848);       // 12.8 MB
    float* Mtmp          = (float*)(ws + 71390848);                // 196,608 B
    float* Vtmp          = (float*)(ws + 71587456);                // 1,536 B -> end 71,588,992
    // rank overlays the Dbuf region: written in k1, consumed in k3a,
    // before Dbuf's first write in k3b. No extra workspace.
    int* rank            = (int*)(ws + 58590848);                  // 3.2 MB (aliases Dbuf)

    const int* rowp = ei;            // edge_index[0] = source
    const int* colp = ei + N_EDGES;  // edge_index[1] = destination

    hipMemsetAsync(cnt, 0, (size_t)N_NODES * 4, stream);
    hipMemsetAsync(aggH, 0, (size_t)N_NODES * HID * 4, stream);    // layer-0 aggH zero

    k1_hist_mfold<<<1024, 256, 0, stream>>>(colp, cnt, rank, edge_w2, node_w1, edge_b2,
                                            Mtmp, Vtmp);
    k2a_scan1_swizzle<<<SCAN_BLOCKS + 288, 256, 0, stream>>>(cnt, ex, bsums, edge_w1,
                                                             node_w1, node_w2, Mtmp, swz);
    k2b_scan2<<<1, 256, 0, stream>>>(bsums);
    k3a_scatter<<<3125, 256, 0, stream>>>(rowp, colp, ex, bsums, rank, rc_sorted);
    k3b_encoder_sd<<<NODE_TILES, 256, 0, stream>>>(x, enc_w, enc_b, swz /*L0 w1cat*/, h,
                                                   Sbuf, Dbuf);

    for (int L = 0; L < 3; L++) {
        unsigned short* base = swz + (size_t)L * 98304;
        unsigned short* next = swz + (size_t)(L + 1) * 98304;   // w1cat of next layer
        edge_kernel<<<2048, 256, 0, stream>>>(Sbuf, Dbuf, rc_sorted,
                                              edge_b1 + (size_t)L * HID, aggH);
        if (L < 2) {
            node_kernel<0><<<NODE_TILES, 256, 0, stream>>>(
                h, aggH, cnt,
                base + 49152, node_b1 + (size_t)L * HID, Vtmp + (size_t)L * HID,
                base + 81920, node_b2 + (size_t)L * HID,
                next, Sbuf, Dbuf, dec_w, dec_b, (float*)d_out);
        } else {
            node_kernel<1><<<NODE_TILES, 256, 0, stream>>>(
                h, aggH, cnt,
                base + 49152, node_b1 + (size_t)L * HID, Vtmp + (size_t)L * HID,
                base + 81920, node_b2 + (size_t)L * HID,
                base /*unused*/, Sbuf, Dbuf, dec_w, dec_b, (float*)d_out);
        }
    }
}

// Round 17
// 388.643 us; speedup vs baseline: 2.7756x; 1.0434x over previous
//
#include <hip/hip_runtime.h>
#include <hip/hip_bf16.h>
#include <stdint.h>

#define N_NODES 50000
#define N_EDGES 800000
#define HID 128
#define NODE_IN 16
#define NODE_OUT 3
#define EDGE_TILES 12500   // 800000 / 64
#define NODE_TILES 782     // ceil(50000 / 64)
#define SCAN_BLOCKS 196    // ceil(50000 / 256)

typedef __attribute__((ext_vector_type(8))) short short8;
typedef __attribute__((ext_vector_type(4))) float f32x4;

__device__ __forceinline__ unsigned short f2bf(float f) {
    union { float f; unsigned int u; } v; v.f = f;
    unsigned int u = v.u;
    u += 0x7fff + ((u >> 16) & 1);   // round-to-nearest-even
    return (unsigned short)(u >> 16);
}
__device__ __forceinline__ float bf2f(unsigned short s) {
    union { unsigned int u; float f; } v; v.u = ((unsigned int)s) << 16;
    return v.f;
}
__device__ __forceinline__ float bfu_lo(unsigned int u) {
    union { unsigned int u; float f; } v; v.u = u << 16; return v.f;
}
__device__ __forceinline__ float bfu_hi(unsigned int u) {
    union { unsigned int u; float f; } v; v.u = u & 0xffff0000u; return v.f;
}

// ---------------- K1: degree histogram (+ per-edge rank) + M-fold ----------------
__global__ void k1_hist_mfold(const int* __restrict__ colp, int* __restrict__ cnt,
                              int* __restrict__ rank,
                              const float* __restrict__ edge_w2, const float* __restrict__ node_w1,
                              const float* __restrict__ edge_b2,
                              float* __restrict__ Mtmp, float* __restrict__ Vtmp) {
    for (int e = blockIdx.x * 256 + threadIdx.x; e < N_EDGES; e += gridDim.x * 256)
        rank[e] = atomicAdd(&cnt[colp[e]], 1);   // old value = within-dest rank
    for (int d = blockIdx.x * 256 + threadIdx.x; d < 3 * 16384; d += gridDim.x * 256) {
        int L = d / 16384, rem = d & 16383;
        int k = rem >> 7, n = rem & 127;
        const float* w2  = edge_w2 + (size_t)L * 16384;
        const float* w1b = node_w1 + (size_t)L * 32768 + 16384;   // bottom-half rows
        float acc = 0.f;
        #pragma unroll 4
        for (int j = 0; j < 128; j++) acc += w2[k * 128 + j] * w1b[j * 128 + n];
        Mtmp[d] = acc;
        if (k == 0) {
            const float* b2 = edge_b2 + (size_t)L * 128;
            float vv = 0.f;
            #pragma unroll 4
            for (int j = 0; j < 128; j++) vv += b2[j] * w1b[j * 128 + n];
            Vtmp[L * 128 + n] = vv;
        }
    }
}

// ---------------- K2a: parallel scan1 (blocks < SCAN_BLOCKS) + weight swizzles ----------------
// swz per-layer layout: +0 edge w1cat (32768), [32768..49152) unused,
//                       +49152 node w1-modified [W1top; M] (32768), +81920 node w2 (16384)
__global__ __launch_bounds__(256) void k2a_scan1_swizzle(
    const int* __restrict__ cnt, int* __restrict__ ex, int* __restrict__ bsums,
    const float* __restrict__ edge_w1, const float* __restrict__ node_w1,
    const float* __restrict__ node_w2, const float* __restrict__ Mtmp,
    unsigned short* __restrict__ swz) {
    __shared__ int s[256];
    int b = blockIdx.x, t = threadIdx.x;
    if (b < SCAN_BLOCKS) {
        int i = b * 256 + t;
        int v = (i < N_NODES) ? cnt[i] : 0;
        s[t] = v;
        __syncthreads();
        for (int off = 1; off < 256; off <<= 1) {
            int u = (t >= off) ? s[t - off] : 0;
            __syncthreads();
            s[t] += u;
            __syncthreads();
        }
        if (i < N_NODES) ex[i] = s[t] - v;
        if (t == 255) bsums[b] = s[255];
    } else {
        for (int d = (b - SCAN_BLOCKS) * 256 + t; d < 3 * 98304;
             d += (gridDim.x - SCAN_BLOCKS) * 256) {
            int L = d / 98304;
            int rem = d - L * 98304;
            unsigned short* base = swz + L * 98304;
            if (rem < 32768) {
                // edge w1 combined [128 x 256] B-frags (16 n-tiles)
                const float* w1 = edge_w1 + (size_t)L * 32768;
                int j = rem & 7, ll = (rem >> 3) & 63, tt = rem >> 9;
                int nt = tt & 15, kt = tt >> 4;
                int k = kt * 32 + ((ll >> 4) << 3) + j;
                int cc = nt * 16 + (ll & 15);
                float v = (cc < 128) ? w1[k * 128 + cc] : w1[(128 + k) * 128 + (cc - 128)];
                base[rem] = f2bf(v);
            } else if (rem < 49152) {
                // unused slot (edge w2 folded into node w1 via M)
            } else if (rem < 81920) {
                int d2 = rem - 49152;
                int j = d2 & 7, ll = (d2 >> 3) & 63, tt = d2 >> 9;
                int nt = tt & 7, kt = tt >> 3;
                int k = kt * 32 + ((ll >> 4) << 3) + j, n = (nt << 4) + (ll & 15);
                float v = (k < 128) ? node_w1[(size_t)L * 32768 + k * 128 + n]
                                    : Mtmp[(size_t)L * 16384 + (k - 128) * 128 + n];
                base[rem] = f2bf(v);
            } else {
                int d2 = rem - 81920;
                const float* src = node_w2 + (size_t)L * 16384;
                int j = d2 & 7, ll = (d2 >> 3) & 63, tt = d2 >> 9;
                int nt = tt & 7, kt = tt >> 3;
                int k = kt * 32 + ((ll >> 4) << 3) + j, n = (nt << 4) + (ll & 15);
                base[rem] = f2bf(src[k * 128 + n]);
            }
        }
    }
}

// ---------------- K3a: scatter with inline scan2 (atomic-free, packed 8B writes) ----------------
__global__ __launch_bounds__(256) void k3a_scatter(
    const int* __restrict__ rowp, const int* __restrict__ colp,
    const int* __restrict__ ex, const int* __restrict__ bsums,
    const int* __restrict__ rank, int2* __restrict__ rc_sorted) {
    __shared__ int sc[256];
    __shared__ int ls[SCAN_BLOCKS];
    int t = threadIdx.x;
    // redundant per-block exclusive scan of the 196 block sums (replaces k2b)
    int v = (t < SCAN_BLOCKS) ? bsums[t] : 0;
    sc[t] = v;
    __syncthreads();
    for (int off = 1; off < 256; off <<= 1) {
        int u = (t >= off) ? sc[t - off] : 0;
        __syncthreads();
        sc[t] += u;
        __syncthreads();
    }
    if (t < SCAN_BLOCKS) ls[t] = sc[t] - v;
    __syncthreads();

    int e = blockIdx.x * 256 + t;
    if (e >= N_EDGES) return;
    int c = colp[e];
    int pos = ex[c] + ls[c >> 8] + rank[e];
    rc_sorted[pos] = make_int2(rowp[e], c);
}

// ---------------- K3b: encoder + S/D layer 0 + aggH zeroing ----------------
__global__ __launch_bounds__(256, 4) void k3b_encoder_sd(
    const float* __restrict__ x, const float* __restrict__ enc_w, const float* __restrict__ enc_b,
    const unsigned short* __restrict__ w1c, unsigned short* __restrict__ h,
    unsigned short* __restrict__ S, unsigned short* __restrict__ D, float* __restrict__ aggH)
{
    __shared__ float wts[NODE_IN * HID];
    __shared__ float bts[HID];
    __shared__ float xs[64][NODE_IN];
    __shared__ unsigned short hs[64][136];
    int t = threadIdx.x, wave = t >> 6, l = t & 63, q = l >> 4, l16 = l & 15;
    int n0 = blockIdx.x * 64;
    int nt0s = wave * 4;

    for (int i = t; i < NODE_IN * HID; i += 256) wts[i] = enc_w[i];
    if (t < HID) bts[t] = enc_b[t];
    for (int i = t; i < 64 * NODE_IN; i += 256) {
        int nl = i >> 4, ii = i & 15;
        int n = n0 + nl;
        xs[nl][ii] = (n < N_NODES) ? x[n * NODE_IN + ii] : 0.f;
    }
    // zero this tile's aggH rows (exclusive ownership; replaces 25.6 MB memset)
    for (int o = t; o < 64 * 32; o += 256) {
        int nl = o >> 5, c4 = o & 31;
        int n = n0 + nl;
        if (n < N_NODES) *(f32x4*)&aggH[n * HID + c4 * 4] = (f32x4){0.f, 0.f, 0.f, 0.f};
    }
    short8 wr[4][4];
    #pragma unroll
    for (int kt = 0; kt < 4; kt++)
        #pragma unroll
        for (int i = 0; i < 4; i++)
            wr[kt][i] = *(const short8*)(w1c + ((kt * 16 + nt0s + i) * 64 + l) * 8);
    __syncthreads();

    for (int o = t; o < 64 * HID; o += 256) {
        int nl = o >> 7, cc = o & 127;
        float acc = bts[cc];
        #pragma unroll
        for (int i = 0; i < NODE_IN; i++) acc += xs[nl][i] * wts[i * HID + cc];
        unsigned short hb = f2bf(acc);
        hs[nl][cc] = hb;
        int n = n0 + nl;
        if (n < N_NODES) h[n * HID + cc] = hb;
    }
    __syncthreads();

    f32x4 acc[4][4];
    #pragma unroll
    for (int g = 0; g < 4; g++)
        #pragma unroll
        for (int i = 0; i < 4; i++) acc[g][i] = (f32x4){0.f, 0.f, 0.f, 0.f};
    #pragma unroll
    for (int kt = 0; kt < 4; kt++) {
        #pragma unroll
        for (int g = 0; g < 4; g++) {
            short8 a = *(const short8*)&hs[g * 16 + l16][kt * 32 + q * 8];
            #pragma unroll
            for (int i = 0; i < 4; i++)
                acc[g][i] = __builtin_amdgcn_mfma_f32_16x16x32_bf16(a, wr[kt][i], acc[g][i], 0, 0, 0);
        }
    }
    #pragma unroll
    for (int i = 0; i < 4; i++) {
        int cc = (nt0s + i) * 16 + l16;
        #pragma unroll
        for (int g = 0; g < 4; g++)
            #pragma unroll
            for (int r = 0; r < 4; r++) {
                int n = n0 + g * 16 + q * 4 + r;
                if (n < N_NODES) {
                    unsigned short v = f2bf(acc[g][i][r]);
                    if (cc < 128) S[n * HID + cc] = v;
                    else          D[n * HID + (cc - 128)] = v;
                }
            }
    }
}

// ---------------- edge: staged gather + relu(bf16 LDS) + fp32 segreduce ----------------
// 3-barrier structure; hid_s in bf16 -> 17.9 KB LDS -> 8 blocks/CU.
__global__ __launch_bounds__(256, 8) void edge_kernel(
    const unsigned short* __restrict__ S, const unsigned short* __restrict__ D,
    const int2* __restrict__ rc_sorted,
    const float* __restrict__ b1, float* __restrict__ aggH)
{
    __shared__ unsigned short hid_s[64][136];   // bf16 relu outputs, 17,408 B
    __shared__ int row_s[64], col_s[64];        //    512 B
    int t = threadIdx.x;
    int ch = t & 15;

    float b1v[8];
    #pragma unroll
    for (int j = 0; j < 8; j++) b1v[j] = b1[ch * 8 + j];

    for (int tile = blockIdx.x; tile < EDGE_TILES; tile += gridDim.x) {
        int e0 = tile * 64;
        if (t < 64) {
            int2 rc = rc_sorted[e0 + t];
            row_s[t] = rc.x;
            col_s[t] = rc.y;
        }
        __syncthreads();

        #pragma unroll
        for (int it = 0; it < 4; it++) {
            int el = it * 16 + (t >> 4);
            int r = row_s[el], c = col_s[el];
            short8 sv = *(const short8*)(S + (size_t)r * HID + ch * 8);
            short8 dv = *(const short8*)(D + (size_t)c * HID + ch * 8);
            short8 o;
            #pragma unroll
            for (int p = 0; p < 4; p++) {
                unsigned int us = ((const unsigned int*)&sv)[p];
                unsigned int ud = ((const unsigned int*)&dv)[p];
                float v0 = bfu_lo(us) + bfu_lo(ud) + b1v[p * 2];
                float v1 = bfu_hi(us) + bfu_hi(ud) + b1v[p * 2 + 1];
                ((unsigned short*)&o)[p * 2]     = f2bf(v0 > 0.f ? v0 : 0.f);
                ((unsigned short*)&o)[p * 2 + 1] = f2bf(v1 > 0.f ? v1 : 0.f);
            }
            *(short8*)&hid_s[el][ch * 8] = o;
        }
        __syncthreads();

        {
            int c = t & 127;
            int h2 = t >> 7;
            int r0 = h2 * 32;
            float accv = 0.f;
            int cur = col_s[r0];
            #pragma unroll 4
            for (int r = r0; r < r0 + 32; r++) {
                accv += bf2f(hid_s[r][c]);
                int nxt = (r == r0 + 31) ? -1 : col_s[r + 1];
                if (nxt != cur) {
                    unsafeAtomicAdd(&aggH[cur * HID + c], accv);
                    accv = 0.f;
                    cur = nxt;
                }
            }
        }
        __syncthreads();
    }
}

// ---------------- node MLP (folded GEMM1) + residual + (next S/D | decoder) ----------------
template<int LAST>
__global__ __launch_bounds__(256, 4) void node_kernel(
    unsigned short* __restrict__ h, float* __restrict__ aggH, const int* __restrict__ cnt,
    const unsigned short* __restrict__ w1m_s, const float* __restrict__ b1,
    const float* __restrict__ vfold,
    const unsigned short* __restrict__ w2s, const float* __restrict__ b2,
    const unsigned short* __restrict__ w1c_next,
    unsigned short* __restrict__ S, unsigned short* __restrict__ D,
    const float* __restrict__ dec_w, const float* __restrict__ dec_b, float* __restrict__ out)
{
    __shared__ unsigned short in_h[64][136];   // old h -> new h after residual
    __shared__ unsigned short in_a[64][136];   // bf16(aggH); reused as hid after GEMM1
    __shared__ int cnt_s[64];
    __shared__ float dw[HID * NODE_OUT];
    __shared__ float db[NODE_OUT];
    int t = threadIdx.x, wave = t >> 6, l = t & 63, q = l >> 4, l16 = l & 15;
    int nt0 = wave * 2, nt0s = wave * 4;
    int n0 = blockIdx.x * 64;

    if (LAST) {
        for (int i = t; i < HID * NODE_OUT; i += 256) dw[i] = dec_w[i];
        if (t < NODE_OUT) db[t] = dec_b[t];
    }

    // stage: h -> in_h, bf16(aggH) -> in_a (re-zero aggH for next layer), cnt
    #pragma unroll
    for (int it = 0; it < 8; it++) {
        int g = it * 256 + t;
        int nl = g >> 5, sub = g & 31, half = sub >> 4, li = sub & 15;
        int n = n0 + nl;
        short8 v = (short8){0, 0, 0, 0, 0, 0, 0, 0};
        if (n < N_NODES) {
            if (half == 0) {
                v = *(const short8*)(h + n * HID + li * 8);
            } else {
                float* ap = aggH + n * HID + li * 8;
                f32x4 a0 = *(f32x4*)ap, a1 = *(f32x4*)(ap + 4);
                #pragma unroll
                for (int j = 0; j < 4; j++) {
                    ((unsigned short*)&v)[j]     = f2bf(a0[j]);
                    ((unsigned short*)&v)[4 + j] = f2bf(a1[j]);
                }
                if (!LAST) {
                    *(f32x4*)ap       = (f32x4){0.f, 0.f, 0.f, 0.f};
                    *(f32x4*)(ap + 4) = (f32x4){0.f, 0.f, 0.f, 0.f};
                }
            }
        }
        if (half == 0) *(short8*)&in_h[nl][li * 8] = v;
        else           *(short8*)&in_a[nl][li * 8] = v;
    }
    if (t < 64) cnt_s[t] = (n0 + t < N_NODES) ? cnt[n0 + t] : 0;
    __syncthreads();

    float b1r0 = b1[nt0 * 16 + l16], b1r1 = b1[(nt0 + 1) * 16 + l16];
    float vr0 = vfold[nt0 * 16 + l16], vr1 = vfold[(nt0 + 1) * 16 + l16];
    float b2r0 = b2[nt0 * 16 + l16], b2r1 = b2[(nt0 + 1) * 16 + l16];

    // GEMM1 (K=256, B = [W1top; M] folded): h@W1top + aggH@M
    f32x4 acc[4][2];
    #pragma unroll
    for (int g = 0; g < 4; g++)
        #pragma unroll
        for (int j = 0; j < 2; j++) acc[g][j] = (f32x4){0.f, 0.f, 0.f, 0.f};
    #pragma unroll
    for (int kt = 0; kt < 8; kt++) {
        short8 b0 = *(const short8*)(w1m_s + ((kt * 8 + nt0)     * 64 + l) * 8);
        short8 b1v = *(const short8*)(w1m_s + ((kt * 8 + nt0 + 1) * 64 + l) * 8);
        #pragma unroll
        for (int g = 0; g < 4; g++) {
            short8 a = (kt < 4) ? *(const short8*)&in_h[g * 16 + l16][kt * 32 + q * 8]
                                : *(const short8*)&in_a[g * 16 + l16][(kt - 4) * 32 + q * 8];
            acc[g][0] = __builtin_amdgcn_mfma_f32_16x16x32_bf16(a, b0, acc[g][0], 0, 0, 0);
            acc[g][1] = __builtin_amdgcn_mfma_f32_16x16x32_bf16(a, b1v, acc[g][1], 0, 0, 0);
        }
    }
    __syncthreads();   // all in_a reads complete before hid overwrite

    // epilogue: + b1 + deg*v -> relu -> hid (aliases in_a)
    #pragma unroll
    for (int j = 0; j < 2; j++) {
        float bv = j ? b1r1 : b1r0;
        float vv = j ? vr1 : vr0;
        #pragma unroll
        for (int g = 0; g < 4; g++)
            #pragma unroll
            for (int r = 0; r < 4; r++) {
                int m2 = g * 16 + q * 4 + r;
                float v = acc[g][j][r] + bv + (float)cnt_s[m2] * vv;
                v = v > 0.f ? v : 0.f;
                in_a[m2][(nt0 + j) * 16 + l16] = f2bf(v);
            }
    }
    __syncthreads();

    // GEMM2n (K=128) -> residual -> h + in_h
    f32x4 acc2[4][2];
    #pragma unroll
    for (int g = 0; g < 4; g++)
        #pragma unroll
        for (int j = 0; j < 2; j++) acc2[g][j] = (f32x4){0.f, 0.f, 0.f, 0.f};
    #pragma unroll
    for (int kt = 0; kt < 4; kt++) {
        short8 b0 = *(const short8*)(w2s + ((kt * 8 + nt0)     * 64 + l) * 8);
        short8 b1v = *(const short8*)(w2s + ((kt * 8 + nt0 + 1) * 64 + l) * 8);
        #pragma unroll
        for (int g = 0; g < 4; g++) {
            short8 a = *(const short8*)&in_a[g * 16 + l16][kt * 32 + q * 8];
            acc2[g][0] = __builtin_amdgcn_mfma_f32_16x16x32_bf16(a, b0, acc2[g][0], 0, 0, 0);
            acc2[g][1] = __builtin_amdgcn_mfma_f32_16x16x32_bf16(a, b1v, acc2[g][1], 0, 0, 0);
        }
    }
    #pragma unroll
    for (int j = 0; j < 2; j++) {
        float bv = j ? b2r1 : b2r0;
        #pragma unroll
        for (int g = 0; g < 4; g++)
            #pragma unroll
            for (int r = 0; r < 4; r++) {
                float v = acc2[g][j][r] + bv;
                int m2 = g * 16 + q * 4 + r;
                int n = n0 + m2;
                if (n < N_NODES) {
                    int c = (nt0 + j) * 16 + l16;
                    unsigned short nh = f2bf(bf2f(in_h[m2][c]) + v);   // residual (same-thread cell)
                    if (!LAST) h[n * HID + c] = nh;
                    in_h[m2][c] = nh;
                }
            }
    }
    __syncthreads();

    if (!LAST) {
        // next-layer S/D from new h (in_h), in 2 register-light passes
        #pragma unroll
        for (int p = 0; p < 2; p++) {
            short8 wr[4][2];
            #pragma unroll
            for (int kt = 0; kt < 4; kt++) {
                wr[kt][0] = *(const short8*)(w1c_next + ((kt * 16 + nt0s + p * 2)     * 64 + l) * 8);
                wr[kt][1] = *(const short8*)(w1c_next + ((kt * 16 + nt0s + p * 2 + 1) * 64 + l) * 8);
            }
            f32x4 accs[4][2];
            #pragma unroll
            for (int g = 0; g < 4; g++)
                #pragma unroll
                for (int i = 0; i < 2; i++) accs[g][i] = (f32x4){0.f, 0.f, 0.f, 0.f};
            #pragma unroll
            for (int kt = 0; kt < 4; kt++) {
                #pragma unroll
                for (int g = 0; g < 4; g++) {
                    short8 a = *(const short8*)&in_h[g * 16 + l16][kt * 32 + q * 8];
                    accs[g][0] = __builtin_amdgcn_mfma_f32_16x16x32_bf16(a, wr[kt][0], accs[g][0], 0, 0, 0);
                    accs[g][1] = __builtin_amdgcn_mfma_f32_16x16x32_bf16(a, wr[kt][1], accs[g][1], 0, 0, 0);
                }
            }
            #pragma unroll
            for (int i = 0; i < 2; i++) {
                int c = (nt0s + p * 2 + i) * 16 + l16;
                #pragma unroll
                for (int g = 0; g < 4; g++)
                    #pragma unroll
                    for (int r = 0; r < 4; r++) {
                        int n = n0 + g * 16 + q * 4 + r;
                        if (n < N_NODES) {
                            unsigned short v = f2bf(accs[g][i][r]);
                            if (c < 128) S[n * HID + c] = v;
                            else         D[n * HID + (c - 128)] = v;
                        }
                    }
            }
        }
    } else {
        // decoder: out = new_h @ dec_w + dec_b
        if (t < 64 * NODE_OUT) {
            int nl = t / 3, o = t - 3 * nl;
            int n = n0 + nl;
            if (n < N_NODES) {
                float a = db[o];
                #pragma unroll 4
                for (int k = 0; k < HID; k++) a += bf2f(in_h[nl][k]) * dw[k * 3 + o];
                out[n * 3 + o] = a;
            }
        }
    }
}

extern "C" void kernel_launch(void* const* d_in, const int* in_sizes, int n_in,
                              void* d_out, int out_size, void* d_ws, size_t ws_size,
                              hipStream_t stream) {
    const float* x       = (const float*)d_in[0];
    const int*   ei      = (const int*)d_in[1];
    const float* enc_w   = (const float*)d_in[2];
    const float* enc_b   = (const float*)d_in[3];
    const float* dec_w   = (const float*)d_in[4];
    const float* dec_b   = (const float*)d_in[5];
    const float* edge_w1 = (const float*)d_in[6];
    const float* edge_b1 = (const float*)d_in[7];
    const float* edge_w2 = (const float*)d_in[8];
    const float* edge_b2 = (const float*)d_in[9];
    const float* node_w1 = (const float*)d_in[10];
    const float* node_b1 = (const float*)d_in[11];
    const float* node_w2 = (const float*)d_in[12];
    const float* node_b2 = (const float*)d_in[13];

    char* ws = (char*)d_ws;
    unsigned short* h    = (unsigned short*)ws;                    // 12.8 MB
    float*          aggH = (float*)(ws + 12800000);                // 25.6 MB
    unsigned short* swz  = (unsigned short*)(ws + 38400000);       // 589,824 B
    int* cnt             = (int*)(ws + 38989824);                  // 200,000 B (degrees)
    int* ex              = (int*)(ws + 39189824);                  // 200,000 B
    int* bsums           = (int*)(ws + 39389824);                  // 1,024 B
    int2* rc_sorted      = (int2*)(ws + 39390848);                 // 6.4 MB
    unsigned short* Sbuf = (unsigned short*)(ws + 45790848);       // 12.8 MB
    unsigned short* Dbuf = (unsigned short*)(ws + 58590848);       // 12.8 MB
    float* Mtmp          = (float*)(ws + 71390848);                // 196,608 B
    float* Vtmp          = (float*)(ws + 71587456);                // 1,536 B -> end 71,588,992
    // rank overlays the Dbuf region: written in k1, consumed in k3a,
    // before Dbuf's first write in k3b. No extra workspace.
    int* rank            = (int*)(ws + 58590848);                  // 3.2 MB (aliases Dbuf)

    const int* rowp = ei;            // edge_index[0] = source
    const int* colp = ei + N_EDGES;  // edge_index[1] = destination

    hipMemsetAsync(cnt, 0, (size_t)N_NODES * 4, stream);

    k1_hist_mfold<<<1024, 256, 0, stream>>>(colp, cnt, rank, edge_w2, node_w1, edge_b2,
                                            Mtmp, Vtmp);
    k2a_scan1_swizzle<<<SCAN_BLOCKS + 288, 256, 0, stream>>>(cnt, ex, bsums, edge_w1,
                                                             node_w1, node_w2, Mtmp, swz);
    k3a_scatter<<<3125, 256, 0, stream>>>(rowp, colp, ex, bsums, rank, rc_sorted);
    k3b_encoder_sd<<<NODE_TILES, 256, 0, stream>>>(x, enc_w, enc_b, swz /*L0 w1cat*/, h,
                                                   Sbuf, Dbuf, aggH);

    for (int L = 0; L < 3; L++) {
        unsigned short* base = swz + (size_t)L * 98304;
        unsigned short* next = swz + (size_t)(L + 1) * 98304;   // w1cat of next layer
        edge_kernel<<<2048, 256, 0, stream>>>(Sbuf, Dbuf, rc_sorted,
                                              edge_b1 + (size_t)L * HID, aggH);
        if (L < 2) {
            node_kernel<0><<<NODE_TILES, 256, 0, stream>>>(
                h, aggH, cnt,
                base + 49152, node_b1 + (size_t)L * HID, Vtmp + (size_t)L * HID,
                base + 81920, node_b2 + (size_t)L * HID,
                next, Sbuf, Dbuf, dec_w, dec_b, (float*)d_out);
        } else {
            node_kernel<1><<<NODE_TILES, 256, 0, stream>>>(
                h, aggH, cnt,
                base + 49152, node_b1 + (size_t)L * HID, Vtmp + (size_t)L * HID,
                base + 81920, node_b2 + (size_t)L * HID,
                base /*unused*/, Sbuf, Dbuf, dec_w, dec_b, (float*)d_out);
        }
    }
}